// Round 6
// baseline (9483.248 us; speedup 1.0000x reference)
//
#include <hip/hip_runtime.h>
#include <hip/hip_fp16.h>
#include <cstddef>

#define T_LEN 4096
#define HID 150
#define G4 600
#define NC 300

typedef __attribute__((ext_vector_type(8))) short bf16x8;      // 8 bf16 = 4 VGPRs
typedef __attribute__((ext_vector_type(8))) _Float16 f16x8;    // 8 fp16 = 4 VGPRs
typedef __attribute__((ext_vector_type(4))) float f32x4;

// raw barrier: waits LDS ops only, leaves global loads/stores in flight
__device__ __forceinline__ void barrier_lgkm() {
  asm volatile("s_waitcnt lgkmcnt(0)\n\ts_barrier" ::: "memory");
}

__device__ __forceinline__ float fsig(float x) {
  return __builtin_amdgcn_rcpf(1.f + __expf(-x));
}
__device__ __forceinline__ float ftanh(float x) {
  float ax = fabsf(x);
  float e = __expf(2.f * ax);
  float t = 1.f - 2.f * __builtin_amdgcn_rcpf(e + 1.f);
  return copysignf(t, x);
}
__device__ __forceinline__ unsigned short f2bf(float f) {  // RNE fp32->bf16
  unsigned u = __builtin_bit_cast(unsigned, f);
  u += 0x7fff + ((u >> 16) & 1);
  return (unsigned short)(u >> 16);
}

// ---------------- LSTM scan via MFMA with gate-permuted weights ----------------
// 4 chains, one block (8 waves) each. g = h @ WhhT via 16x16x32 bf16 MFMA,
// A row0 = h. B rows are PERMUTED so lane l (<16) of wave wv receives all four
// gates of its channel in acc[0..3][0]:
//   j<4 : slot(wv,j,l) -> Whh row j*150 + (16*wv+l)      (channels 0..127)
//   j==4: u=16*wv+l; u<88 -> row (u%4)*150 + 128 + u/4   (channels 128..149,
//         4 gates in 4 adjacent lanes; in-wave shfl gathers them)
// Gate math + c-state stay lane-resident: no g LDS scatter, ONE barrier/step.
__global__ __launch_bounds__(512, 2) void lstm_scan(
    const float* __restrict__ whh_solv, const float* __restrict__ whh_solu,
    const float* __restrict__ xg_base,
    float* __restrict__ out_solv, float* __restrict__ out_solu, int layer)
{
  __shared__ __align__(16) unsigned short h_bf[160];  // bf16 h, zeros beyond 150
  const int c = blockIdx.x;
  const int net = c >> 1, dir = c & 1;
  const float* Whh = (net ? whh_solu : whh_solv) + (size_t)(layer * 2 + dir) * (G4 * HID);
  const float* xg = xg_base + (size_t)c * T_LEN * G4;
  float* out = (net ? out_solu : out_solv) + dir * HID;  // row stride NC
  const int tid = threadIdx.x;
  const int lane = tid & 63, wv = tid >> 6;
  const int l = lane & 15, q = lane >> 4;   // frag col & k-quad
  const int u = 16 * wv + l;                // 0..127
  const bool gate_lane = (lane < 16);
  const bool sec_lane = gate_lane && ((l & 3) == 0) && (u < 88);
  const int cp = u;                          // primary channel (0..127)
  const int cs = 128 + (u >> 2);             // secondary channel (if sec_lane)

  // B-fragments with permuted rows; lane holds col=l, k=kk*32+q*8+i
  bf16x8 bfr[5][5];  // [j][kk]
#pragma unroll
  for (int j = 0; j < 5; j++) {
    int row;
    if (j < 4) row = j * HID + u;
    else       row = (u < 88) ? (u & 3) * HID + 128 + (u >> 2) : -1;
#pragma unroll
    for (int kk = 0; kk < 5; kk++) {
      bf16x8 b;
#pragma unroll
      for (int i = 0; i < 8; i++) {
        const int k = kk * 32 + q * 8 + i;
        const float v = (row >= 0 && k < HID) ? Whh[(size_t)row * HID + k] : 0.f;
        b[i] = (short)f2bf(v);
      }
      bfr[j][kk] = b;
    }
  }
  if (tid < 160) h_bf[tid] = 0;
  float cstp = 0.f, csts = 0.f;
  float xp0 = 0.f, xp1 = 0.f, xp2 = 0.f, xp3 = 0.f;
  float xs0 = 0.f, xs1 = 0.f, xs2 = 0.f, xs3 = 0.f;
  {
    const int t0 = dir ? (T_LEN - 1) : 0;
    const float* base = xg + (size_t)t0 * G4;
    if (gate_lane) { xp0 = base[cp]; xp1 = base[HID + cp]; xp2 = base[2 * HID + cp]; xp3 = base[3 * HID + cp]; }
    if (sec_lane)  { xs0 = base[cs]; xs1 = base[HID + cs]; xs2 = base[2 * HID + cs]; xs3 = base[3 * HID + cs]; }
  }
  // A-frags persist; zeros in lanes l!=0, masked ds_read refreshes row 0
  bf16x8 af[5];
#pragma unroll
  for (int kk = 0; kk < 5; kk++) af[kk] = (bf16x8){0, 0, 0, 0, 0, 0, 0, 0};
  const f32x4 z4 = {0.f, 0.f, 0.f, 0.f};
  barrier_lgkm();

  for (int s = 0; s < T_LEN; s++) {
    const int t = dir ? (T_LEN - 1 - s) : s;
    if (l == 0) {
#pragma unroll
      for (int kk = 0; kk < 5; kk++) af[kk] = *(const bf16x8*)&h_bf[kk * 32 + q * 8];
    }
    f32x4 acc[5];
#pragma unroll
    for (int j = 0; j < 4; j++)
      acc[j] = __builtin_amdgcn_mfma_f32_16x16x32_bf16(af[0], bfr[j][0], z4, 0, 0, 0);
    if (wv < 6)
      acc[4] = __builtin_amdgcn_mfma_f32_16x16x32_bf16(af[0], bfr[4][0], z4, 0, 0, 0);
#pragma unroll
    for (int kk = 1; kk < 5; kk++) {
#pragma unroll
      for (int j = 0; j < 4; j++)
        acc[j] = __builtin_amdgcn_mfma_f32_16x16x32_bf16(af[kk], bfr[j][kk], acc[j], 0, 0, 0);
      if (wv < 6)
        acc[4] = __builtin_amdgcn_mfma_f32_16x16x32_bf16(af[kk], bfr[4][kk], acc[4], 0, 0, 0);
    }
    // gate phase: D row0 (lanes 0-15, reg 0) holds the 4 gates of channel cp
    if (gate_lane) {
      const float g4 = acc[4][0];
      const int b4 = lane & ~3;
      const float v0 = __shfl(g4, b4), v1 = __shfl(g4, b4 | 1);
      const float v2 = __shfl(g4, b4 | 2), v3 = __shfl(g4, b4 | 3);
      if (sec_lane) {
        const float si = xs0 + v0, sf = xs1 + v1, sg = xs2 + v2, so = xs3 + v3;
        csts = fsig(sf) * csts + fsig(si) * ftanh(sg);
        const float hs = fsig(so) * ftanh(csts);
        h_bf[cs] = f2bf(hs);
        out[(size_t)t * NC + cs] = hs;
      }
      const float gi = xp0 + acc[0][0], gf = xp1 + acc[1][0];
      const float gg = xp2 + acc[2][0], go = xp3 + acc[3][0];
      cstp = fsig(gf) * cstp + fsig(gi) * ftanh(gg);
      const float hp = fsig(go) * ftanh(cstp);
      h_bf[cp] = f2bf(hp);
      out[(size_t)t * NC + cp] = hp;
      if (s + 1 < T_LEN) {  // prefetch next xg (stays in flight past barrier)
        const int tn = dir ? (T_LEN - 2 - s) : (s + 1);
        const float* base = xg + (size_t)tn * G4;
        xp0 = base[cp]; xp1 = base[HID + cp]; xp2 = base[2 * HID + cp]; xp3 = base[3 * HID + cp];
        if (sec_lane) { xs0 = base[cs]; xs1 = base[HID + cs]; xs2 = base[2 * HID + cs]; xs3 = base[3 * HID + cs]; }
      }
    }
    barrier_lgkm();
  }
}

// ---------------- fp32 -> fp16 conversion helpers ------------------------------
// Wihh[8][640][320]: slot s = l*4 + net*2 + dir, zero-padded rows/cols
__global__ void conv_w(const float* __restrict__ wv, const float* __restrict__ wu,
                       __half* __restrict__ dst)
{
  const int gid = blockIdx.x * 256 + threadIdx.x;
  if (gid >= 8 * 640 * 320) return;
  const int k = gid % 320, j = (gid / 320) % 640, s = gid / (320 * 640);
  const int l = s >> 2, net = (s >> 1) & 1, dir = s & 1;
  float v = 0.f;
  if (j < G4 && k < NC) {
    const float* src = (net ? wu : wv) + (size_t)(l * 2 + dir) * (G4 * NC);
    v = src[(size_t)j * NC + k];
  }
  dst[gid] = __float2half(v);
}

// X fp32 [rows][300] -> Xh fp16 [rows][320] zero-padded
__global__ void conv_x(const float* __restrict__ src, __half* __restrict__ dst, int rows)
{
  const int gid = blockIdx.x * 256 + threadIdx.x;
  if (gid >= rows * 320) return;
  const int k = gid % 320, m = gid / 320;
  dst[gid] = __float2half(k < NC ? src[(size_t)m * NC + k] : 0.f);
}

// X fp32 [4096][300] -> XT fp16 [320][4096] (rows >= 300 zeroed)
__global__ void conv_t(const float* __restrict__ src, __half* __restrict__ dst)
{
  const int gid = blockIdx.x * 256 + threadIdx.x;
  if (gid >= 320 * 4096) return;
  const int m = gid % 4096, f = gid / 4096;
  dst[gid] = __float2half(f < NC ? src[(size_t)m * NC + f] : 0.f);
}

__global__ void zero_f(float* __restrict__ p, int n) {
  const int i = blockIdx.x * 256 + threadIdx.x;
  if (i < n) p[i] = 0.f;
}

// ---------------- xg = X @ Wih^T + b via fp16 MFMA -----------------------------
// grid (64 m-blocks, 4 chains), block 256 (4 waves, 16 rows each). N=640, K=320.
__global__ __launch_bounds__(256) void xg_mfma(
    const __half* __restrict__ Av, const __half* __restrict__ Au,
    const __half* __restrict__ W,   // Wihh + layer*4*640*320
    const float* __restrict__ bihv, const float* __restrict__ bhhv,
    const float* __restrict__ bihu, const float* __restrict__ bhhu,
    float* __restrict__ xg, int layer)
{
  const int tid = threadIdx.x;
  const int lane = tid & 63, wv = tid >> 6;
  const int ln = lane & 15, q = lane >> 4;
  const int chain = blockIdx.y;
  const __half* A = (chain >= 2) ? Au : Av;
  const __half* Wc = W + (size_t)chain * 640 * 320;
  const float* bi = ((chain >= 2) ? bihu : bihv) + (size_t)(layer * 2 + (chain & 1)) * G4;
  const float* bh = ((chain >= 2) ? bhhu : bhhv) + (size_t)(layer * 2 + (chain & 1)) * G4;
  float* C = xg + (size_t)chain * T_LEN * G4;
  const int m0 = blockIdx.x * 64 + wv * 16;
  const __half* Arow = A + (size_t)(m0 + ln) * 320;

  for (int nc = 0; nc < 4; nc++) {       // 4 chunks x 160 cols
    f32x4 acc[10];
#pragma unroll
    for (int j = 0; j < 10; j++) acc[j] = (f32x4){0.f, 0.f, 0.f, 0.f};
    for (int kk = 0; kk < 10; kk++) {
      const f16x8 afr = *(const f16x8*)(Arow + kk * 32 + q * 8);
#pragma unroll
      for (int j = 0; j < 10; j++) {
        const int n = nc * 160 + j * 16 + ln;
        const f16x8 bfr = *(const f16x8*)(Wc + (size_t)n * 320 + kk * 32 + q * 8);
        acc[j] = __builtin_amdgcn_mfma_f32_16x16x32_f16(afr, bfr, acc[j], 0, 0, 0);
      }
    }
#pragma unroll
    for (int j = 0; j < 10; j++) {
      const int n = nc * 160 + j * 16 + ln;
      if (n < G4) {
        const float bias = bi[n] + bh[n];
#pragma unroll
        for (int r = 0; r < 4; r++)
          C[(size_t)(m0 + q * 4 + r) * G4 + n] = acc[j][r] + bias;
      }
    }
  }
}

// ------- attention pass 1: sums[m] = sum_n exp(S[m][n] - 30), S = Hh @ Gh^T ----
// grid (64 m-blocks, 4 n-quadrants), block 256. Softmax is shift-invariant: a
// global constant shift replaces per-row max machinery (clamp = overflow guard).
__global__ __launch_bounds__(256) void s_pass1(
    const __half* __restrict__ Hh, const __half* __restrict__ Gh,
    float* __restrict__ sums)
{
  const int tid = threadIdx.x;
  const int lane = tid & 63, wv = tid >> 6;
  const int ln = lane & 15, q = lane >> 4;
  const int m0 = blockIdx.x * 64 + wv * 16;
  const __half* Arow = Hh + (size_t)(m0 + ln) * 320;
  f16x8 afr[10];
#pragma unroll
  for (int kk = 0; kk < 10; kk++) afr[kk] = *(const f16x8*)(Arow + kk * 32 + q * 8);
  float rs[4] = {0.f, 0.f, 0.f, 0.f};
  const int nt0 = blockIdx.y * 64;
  for (int nt = 0; nt < 64; nt++) {
    const __half* Brow = Gh + (size_t)(16 * (nt0 + nt) + ln) * 320;
    f32x4 acc = (f32x4){0.f, 0.f, 0.f, 0.f};
#pragma unroll
    for (int kk = 0; kk < 10; kk++) {
      const f16x8 bfr = *(const f16x8*)(Brow + kk * 32 + q * 8);
      acc = __builtin_amdgcn_mfma_f32_16x16x32_f16(afr[kk], bfr, acc, 0, 0, 0);
    }
#pragma unroll
    for (int r = 0; r < 4; r++) rs[r] += __expf(fminf(acc[r] - 30.f, 80.f));
  }
#pragma unroll
  for (int m = 1; m <= 8; m <<= 1)
#pragma unroll
    for (int r = 0; r < 4; r++) rs[r] += __shfl_xor(rs[r], m);
  if (ln == 0) {
#pragma unroll
    for (int r = 0; r < 4; r++) atomicAdd(&sums[m0 + q * 4 + r], rs[r]);
  }
}

__global__ void invert_k(const float* __restrict__ sums, float* __restrict__ il) {
  const int i = blockIdx.x * 256 + threadIdx.x;
  if (i < 4096) il[i] = 1.f / sums[i];
}

// ------- attention pass 2: a = exp(S-30)*il[m] -> AH fp16 (row-major only) -----
__global__ __launch_bounds__(256) void s_pass2(
    const __half* __restrict__ Hh, const __half* __restrict__ Gh,
    const float* __restrict__ il, __half* __restrict__ AH)
{
  const int tid = threadIdx.x;
  const int lane = tid & 63, wv = tid >> 6;
  const int ln = lane & 15, q = lane >> 4;
  const int m0 = blockIdx.x * 64 + wv * 16;
  const __half* Arow = Hh + (size_t)(m0 + ln) * 320;
  f16x8 afr[10];
#pragma unroll
  for (int kk = 0; kk < 10; kk++) afr[kk] = *(const f16x8*)(Arow + kk * 32 + q * 8);
  float ilr[4];
#pragma unroll
  for (int r = 0; r < 4; r++) ilr[r] = il[m0 + q * 4 + r];
  const int nt0 = blockIdx.y * 64;
  for (int nt = 0; nt < 64; nt++) {
    const int n = 16 * (nt0 + nt) + ln;
    const __half* Brow = Gh + (size_t)n * 320;
    f32x4 acc = (f32x4){0.f, 0.f, 0.f, 0.f};
#pragma unroll
    for (int kk = 0; kk < 10; kk++) {
      const f16x8 bfr = *(const f16x8*)(Brow + kk * 32 + q * 8);
      acc = __builtin_amdgcn_mfma_f32_16x16x32_f16(afr[kk], bfr, acc, 0, 0, 0);
    }
#pragma unroll
    for (int r = 0; r < 4; r++) {
      const float a = __expf(fminf(acc[r] - 30.f, 80.f)) * ilr[r];
      AH[(size_t)(m0 + q * 4 + r) * 4096 + n] = __float2half(a);
    }
  }
}

// ------- P = AH @ GhT' : M=4096, N=320(store 300), K=4096; A read row-major ----
__global__ __launch_bounds__(256) void p_mfma(
    const __half* __restrict__ AH, const __half* __restrict__ GhT,
    float* __restrict__ Pb)
{
  const int tid = threadIdx.x;
  const int lane = tid & 63, wv = tid >> 6;
  const int ln = lane & 15, q = lane >> 4;
  const int m0 = blockIdx.x * 64 + wv * 16;
  const __half* Arow = AH + (size_t)(m0 + ln) * 4096;

  for (int nc = 0; nc < 2; nc++) {
    f32x4 acc[10];
#pragma unroll
    for (int j = 0; j < 10; j++) acc[j] = (f32x4){0.f, 0.f, 0.f, 0.f};
    for (int kk = 0; kk < 128; kk++) {
      const f16x8 afr = *(const f16x8*)(Arow + kk * 32 + q * 8);
#pragma unroll
      for (int j = 0; j < 10; j++) {
        const int n = nc * 160 + j * 16 + ln;
        const f16x8 bfr = *(const f16x8*)(GhT + (size_t)n * 4096 + kk * 32 + q * 8);
        acc[j] = __builtin_amdgcn_mfma_f32_16x16x32_f16(afr, bfr, acc[j], 0, 0, 0);
      }
    }
#pragma unroll
    for (int j = 0; j < 10; j++) {
      const int n = nc * 160 + j * 16 + ln;
      if (n < NC) {
#pragma unroll
        for (int r = 0; r < 4; r++)
          Pb[(size_t)(m0 + q * 4 + r) * NC + n] = acc[j][r];
      }
    }
  }
}

// ------- Q[j][f] = sum_i a[i][j] H[i][f]: a-operand transposed via LDS ---------
// grid 64 (j-blocks of 64), block 256 (4 waves, 16 j-rows each). K=4096 in 64-chunks.
__global__ __launch_bounds__(256) void qt_mfma(
    const __half* __restrict__ AH, const __half* __restrict__ HhT,
    float* __restrict__ Qb)
{
  __shared__ __align__(16) _Float16 Ats[64][72];  // [j-local][i-local], pitch 144 B
  const int tid = threadIdx.x;
  const int lane = tid & 63, wv = tid >> 6;
  const int ln = lane & 15, q = lane >> 4;
  const int j0 = blockIdx.x * 64;
  f32x4 acc[20];
#pragma unroll
  for (int j = 0; j < 20; j++) acc[j] = (f32x4){0.f, 0.f, 0.f, 0.f};
  const int il8 = tid >> 2, j8 = (tid & 3) * 16;  // staging role

  for (int ic = 0; ic < 4096; ic += 64) {
    __syncthreads();  // protect LDS tile reuse
    {
      const __half* src = AH + (size_t)(ic + il8) * 4096 + j0 + j8;
      const f16x8 v0 = *(const f16x8*)src;
      const f16x8 v1 = *(const f16x8*)(src + 8);
#pragma unroll
      for (int jj = 0; jj < 8; jj++) Ats[j8 + jj][il8] = v0[jj];
#pragma unroll
      for (int jj = 0; jj < 8; jj++) Ats[j8 + 8 + jj][il8] = v1[jj];
    }
    __syncthreads();
#pragma unroll
    for (int s = 0; s < 2; s++) {
      const f16x8 afr = *(const f16x8*)&Ats[wv * 16 + ln][s * 32 + q * 8];
      const __half* bbase = HhT + ic + s * 32 + q * 8;
#pragma unroll
      for (int j = 0; j < 20; j++) {
        const f16x8 bfr = *(const f16x8*)(bbase + (size_t)(j * 16 + ln) * 4096);
        acc[j] = __builtin_amdgcn_mfma_f32_16x16x32_f16(afr, bfr, acc[j], 0, 0, 0);
      }
    }
  }
#pragma unroll
  for (int j = 0; j < 20; j++) {
    const int f = j * 16 + ln;
    if (f < NC) {
#pragma unroll
      for (int r = 0; r < 4; r++)
        Qb[(size_t)(j0 + wv * 16 + q * 4 + r) * NC + f] = acc[j][r];
    }
  }
}

// ---------------- tail ---------------------------------------------------------
__global__ void reduce_uv(const float* __restrict__ X, const float* __restrict__ Yp,
                          float* __restrict__ inp, int off)
{
  const int j = threadIdx.x;
  if (j >= NC) return;
  const int r0 = blockIdx.x * 128;
  float s = 0.f;
  for (int r = r0; r < r0 + 128; r++)
    s += fmaxf(X[(size_t)r * NC + j], Yp[(size_t)r * NC + j]);
  atomicAdd(&inp[off + j], s);
}

__global__ void fc1_k(const float* __restrict__ w1, const float* __restrict__ b1,
                      const float* __restrict__ inp, float* __restrict__ x)
{
  const int r = blockIdx.x * 256 + threadIdx.x;
  if (r >= 2000) return;
  float s = b1[r];
  const float* wr = w1 + (size_t)r * 600;
  for (int k = 0; k < 600; k++) s += wr[k] * inp[k];
  x[r] = fmaxf(s, 0.f);
}

__global__ void fc2_k(const float* __restrict__ x, const float* __restrict__ w2,
                      const float* __restrict__ b2, float* __restrict__ outp)
{
  const int tid = threadIdx.x;
  float s = 0.f;
  for (int i = tid; i < 2000; i += 256) s += x[i] * w2[i];
#pragma unroll
  for (int off = 32; off > 0; off >>= 1) s += __shfl_down(s, off);
  __shared__ float red[4];
  if ((tid & 63) == 0) red[tid >> 6] = s;
  __syncthreads();
  if (tid == 0) outp[0] = red[0] + red[1] + red[2] + red[3] + b2[0];
}

// ---------------- launch --------------------------------------------------------
extern "C" void kernel_launch(void* const* d_in, const int* in_sizes, int n_in,
                              void* d_out, int out_size, void* d_ws, size_t ws_size,
                              hipStream_t stream)
{
  const float* in_solv  = (const float*)d_in[0];
  const float* in_solu  = (const float*)d_in[1];
  const float* solv_Wih = (const float*)d_in[2];
  const float* solv_Whh = (const float*)d_in[3];
  const float* solv_bih = (const float*)d_in[4];
  const float* solv_bhh = (const float*)d_in[5];
  const float* solu_Wih = (const float*)d_in[6];
  const float* solu_Whh = (const float*)d_in[7];
  const float* solu_bih = (const float*)d_in[8];
  const float* solu_bhh = (const float*)d_in[9];
  const float* fc1_w = (const float*)d_in[10];
  const float* fc1_b = (const float*)d_in[11];
  const float* fc2_w = (const float*)d_in[12];
  const float* fc2_b = (const float*)d_in[13];
  float* outp = (float*)d_out;
  float* ws = (float*)d_ws;

  // ---- workspace layout (float offsets); peak 17,214,080 fl = 68.9 MB ----
  constexpr size_t off_P   = 0;          // Wihh (819,200 fl) early; P fp32 late
  constexpr size_t off_Q   = 1228800;    // Q fp32
  constexpr size_t off_inp = 2457600;    // 640
  constexpr size_t off_x   = 2458240;    // 2048
  constexpr size_t off_il  = 2460288;    // 4096
  constexpr size_t off_sm  = 2464384;    // 4096 (exp sums)
  constexpr size_t off_xg  = 2468480;    // xg 9,830,400 fl; later AH+HhT/GhT
  constexpr size_t off_L0  = off_xg + (size_t)4 * 2457600;   // L0v/L0u; Avh/Auh; Hh/Gh
  constexpr size_t off_HG  = off_L0 + (size_t)2 * 1228800;   // Hb/Gb; L0vh/L0uh transient

  float*  xg   = ws + off_xg;
  float*  L0v  = ws + off_L0;
  float*  L0u  = L0v + 1228800;
  float*  Hb   = ws + off_HG;
  float*  Gb   = Hb + 1228800;
  float*  Pb   = ws + off_P;
  float*  Qb   = ws + off_Q;
  float*  inp  = ws + off_inp;
  float*  xf   = ws + off_x;
  float*  il   = ws + off_il;
  float*  sums = ws + off_sm;
  __half* Wihh = (__half*)(ws + off_P);            // dead before P written
  __half* Avh  = (__half*)(ws + off_L0);           // dead before L0 written
  __half* Auh  = Avh + 4096 * 320;
  __half* L0vh = (__half*)(ws + off_HG);           // dead before Hb/Gb written
  __half* L0uh = L0vh + 4096 * 320;
  __half* Hh   = (__half*)(ws + off_L0);           // post-scan2 (L0 dead)
  __half* Gh   = Hh + 4096 * 320;
  __half* AH   = (__half*)(ws + off_xg);           // post-scan2 (xg dead)
  __half* HhT  = AH + (size_t)4096 * 4096;
  __half* GhT  = HhT + 320 * 4096;                 // total 9,699,328 < 9,830,400 ok

  // ---- weights + layer-0 inputs to fp16 ----
  conv_w<<<(8 * 640 * 320 + 255) / 256, 256, 0, stream>>>(solv_Wih, solu_Wih, Wihh);
  conv_x<<<(4096 * 320 + 255) / 256, 256, 0, stream>>>(in_solv, Avh, 4096);
  conv_x<<<(4096 * 320 + 255) / 256, 256, 0, stream>>>(in_solu, Auh, 4096);

  // ---- layer 0 ----
  xg_mfma<<<dim3(64, 4), 256, 0, stream>>>(Avh, Auh, Wihh,
      solv_bih, solv_bhh, solu_bih, solu_bhh, xg, 0);
  lstm_scan<<<4, 512, 0, stream>>>(solv_Whh, solu_Whh, xg, L0v, L0u, 0);

  // ---- layer 1 ----
  conv_x<<<(4096 * 320 + 255) / 256, 256, 0, stream>>>(L0v, L0vh, 4096);
  conv_x<<<(4096 * 320 + 255) / 256, 256, 0, stream>>>(L0u, L0uh, 4096);
  xg_mfma<<<dim3(64, 4), 256, 0, stream>>>(L0vh, L0uh, Wihh + (size_t)4 * 640 * 320,
      solv_bih, solv_bhh, solu_bih, solu_bhh, xg, 1);
  lstm_scan<<<4, 512, 0, stream>>>(solv_Whh, solu_Whh, xg, Hb, Gb, 1);

  // ---- attention (xg dead from here; AH/HhT/GhT live in its region) ----
  conv_x<<<(4096 * 320 + 255) / 256, 256, 0, stream>>>(Hb, Hh, 4096);
  conv_x<<<(4096 * 320 + 255) / 256, 256, 0, stream>>>(Gb, Gh, 4096);
  conv_t<<<(320 * 4096 + 255) / 256, 256, 0, stream>>>(Hb, HhT);
  conv_t<<<(320 * 4096 + 255) / 256, 256, 0, stream>>>(Gb, GhT);
  zero_f<<<16, 256, 0, stream>>>(sums, 4096);
  s_pass1<<<dim3(64, 4), 256, 0, stream>>>(Hh, Gh, sums);
  invert_k<<<16, 256, 0, stream>>>(sums, il);
  s_pass2<<<dim3(64, 4), 256, 0, stream>>>(Hh, Gh, il, AH);
  p_mfma<<<64, 256, 0, stream>>>(AH, GhT, Pb);
  qt_mfma<<<64, 256, 0, stream>>>(AH, HhT, Qb);

  // ---- tail ----
  zero_f<<<3, 256, 0, stream>>>(inp, 640);
  reduce_uv<<<32, 320, 0, stream>>>(Hb, Pb, inp, 0);
  reduce_uv<<<32, 320, 0, stream>>>(Gb, Qb, inp, 300);
  fc1_k<<<8, 256, 0, stream>>>(fc1_w, fc1_b, inp, xf);
  fc2_k<<<1, 256, 0, stream>>>(xf, fc2_w, fc2_b, outp);
}

// Round 7
// 8137.318 us; speedup vs baseline: 1.1654x; 1.1654x over previous
//
#include <hip/hip_runtime.h>
#include <hip/hip_fp16.h>
#include <cstddef>

#define T_LEN 4096
#define HID 150
#define G4 600
#define NC 300

typedef __attribute__((ext_vector_type(8))) short bf16x8;      // 8 bf16 = 4 VGPRs
typedef __attribute__((ext_vector_type(8))) _Float16 f16x8;    // 8 fp16 = 4 VGPRs
typedef __attribute__((ext_vector_type(4))) float f32x4;

// raw barrier: waits LDS ops only, leaves global loads/stores in flight
__device__ __forceinline__ void barrier_lgkm() {
  asm volatile("s_waitcnt lgkmcnt(0)\n\ts_barrier" ::: "memory");
}

__device__ __forceinline__ float fsig(float x) {
  return __builtin_amdgcn_rcpf(1.f + __expf(-x));
}
__device__ __forceinline__ float ftanh(float x) {
  float ax = fabsf(x);
  float e = __expf(2.f * ax);
  float t = 1.f - 2.f * __builtin_amdgcn_rcpf(e + 1.f);
  return copysignf(t, x);
}
__device__ __forceinline__ unsigned short f2bf(float f) {  // RNE fp32->bf16
  unsigned u = __builtin_bit_cast(unsigned, f);
  u += 0x7fff + ((u >> 16) & 1);
  return (unsigned short)(u >> 16);
}

// ---------------- LSTM scan via MFMA: 4 chains, one block (16 waves) each ------
// r3 structure (best measured: g_s scatter + 150-thread gate phase), widened to
// 16 waves (4/SIMD) for latency hiding. Wave w owns n-tiles {w, w+16} and, for
// w<8, also w+32 (40 tiles total = 640 gate rows). 10-15 MFMAs per wave.
__global__ __launch_bounds__(1024, 4) void lstm_scan(
    const float* __restrict__ whh_solv, const float* __restrict__ whh_solu,
    const float* __restrict__ xg_base,
    float* __restrict__ out_solv, float* __restrict__ out_solu, int layer)
{
  __shared__ __align__(16) unsigned short h_bf[160];  // bf16 h, zeros beyond 150
  __shared__ float g_s[640];
  const int c = blockIdx.x;
  const int net = c >> 1, dir = c & 1;
  const float* Whh = (net ? whh_solu : whh_solv) + (size_t)(layer * 2 + dir) * (G4 * HID);
  const float* xg = xg_base + (size_t)c * T_LEN * G4;
  float* out = (net ? out_solu : out_solv) + dir * HID;  // row stride NC
  const int tid = threadIdx.x;
  const int lane = tid & 63, wv = tid >> 6;   // wv 0..15
  const int lrow = lane & 15, lq = lane >> 4; // frag row & k-quad
  const bool has3 = (wv < 8);
  const int t0i = wv, t1i = wv + 16, t2i = wv + 32;  // n-tiles

  // B-fragments: B[k][n] = Whh[n][k]; lane holds n=16*tile+lrow, k=kk*32+lq*8+i
  bf16x8 bfr[3][5];  // [tile-slot][kk]
#pragma unroll
  for (int j = 0; j < 3; j++) {
    const int tile = (j == 0) ? t0i : (j == 1) ? t1i : t2i;
    const bool tv = (j < 2) || has3;
    const int jrow = 16 * tile + lrow;
#pragma unroll
    for (int kk = 0; kk < 5; kk++) {
      bf16x8 b;
#pragma unroll
      for (int i = 0; i < 8; i++) {
        const int k = kk * 32 + lq * 8 + i;
        const float v = (tv && jrow < G4 && k < HID) ? Whh[(size_t)jrow * HID + k] : 0.f;
        b[i] = (short)f2bf(v);
      }
      bfr[j][kk] = b;
    }
  }
  if (tid < 160) h_bf[tid] = 0;
  float cst = 0.f;
  float xr0 = 0.f, xr1 = 0.f, xr2 = 0.f, xr3 = 0.f;
  if (tid < HID) {
    const int t0 = dir ? (T_LEN - 1) : 0;
    const float* xgr = xg + (size_t)t0 * G4 + tid;
    xr0 = xgr[0]; xr1 = xgr[HID]; xr2 = xgr[2 * HID]; xr3 = xgr[3 * HID];
  }
  const f32x4 z4 = {0.f, 0.f, 0.f, 0.f};
  barrier_lgkm();

  for (int s = 0; s < T_LEN; s++) {
    const int t = dir ? (T_LEN - 1 - s) : s;
    // A-frags: row0 = h_bf, rows 1-15 zero (r3 style: rebuilt each step)
    bf16x8 af[5];
#pragma unroll
    for (int kk = 0; kk < 5; kk++) {
      bf16x8 a = {0, 0, 0, 0, 0, 0, 0, 0};
      if (lrow == 0) a = *(const bf16x8*)&h_bf[kk * 32 + lq * 8];
      af[kk] = a;
    }
    f32x4 acc0, acc1, acc2;
    acc0 = __builtin_amdgcn_mfma_f32_16x16x32_bf16(af[0], bfr[0][0], z4, 0, 0, 0);
    acc1 = __builtin_amdgcn_mfma_f32_16x16x32_bf16(af[0], bfr[1][0], z4, 0, 0, 0);
    if (has3) acc2 = __builtin_amdgcn_mfma_f32_16x16x32_bf16(af[0], bfr[2][0], z4, 0, 0, 0);
#pragma unroll
    for (int kk = 1; kk < 5; kk++) {
      acc0 = __builtin_amdgcn_mfma_f32_16x16x32_bf16(af[kk], bfr[0][kk], acc0, 0, 0, 0);
      acc1 = __builtin_amdgcn_mfma_f32_16x16x32_bf16(af[kk], bfr[1][kk], acc1, 0, 0, 0);
      if (has3) acc2 = __builtin_amdgcn_mfma_f32_16x16x32_bf16(af[kk], bfr[2][kk], acc2, 0, 0, 0);
    }
    // D row0 lives in lanes 0-15, reg 0
    if (lane < 16) {
      g_s[16 * t0i + lane] = acc0[0];
      g_s[16 * t1i + lane] = acc1[0];
      if (has3) g_s[16 * t2i + lane] = acc2[0];
    }
    barrier_lgkm();
    if (tid < HID) {
      const int n = tid;
      float gi = xr0 + g_s[n];
      float gf = xr1 + g_s[HID + n];
      float gg = xr2 + g_s[2 * HID + n];
      float go = xr3 + g_s[3 * HID + n];
      if (s + 1 < T_LEN) {  // prefetch next xg row (stays in flight past barrier)
        const int tn = dir ? (T_LEN - 2 - s) : (s + 1);
        const float* xgr = xg + (size_t)tn * G4 + n;
        xr0 = xgr[0]; xr1 = xgr[HID]; xr2 = xgr[2 * HID]; xr3 = xgr[3 * HID];
      }
      const float iv = fsig(gi), fv = fsig(gf), gv = ftanh(gg), ov = fsig(go);
      cst = fv * cst + iv * gv;
      const float hv = ov * ftanh(cst);
      h_bf[n] = f2bf(hv);      // matvec input rounded; c/h state stays fp32
      out[(size_t)t * NC + n] = hv;
    }
    barrier_lgkm();
  }
}

// ---------------- fp32 -> fp16 conversion helpers ------------------------------
// Wihh[8][640][320]: slot s = l*4 + net*2 + dir, zero-padded rows/cols
__global__ void conv_w(const float* __restrict__ wv, const float* __restrict__ wu,
                       __half* __restrict__ dst)
{
  const int gid = blockIdx.x * 256 + threadIdx.x;
  if (gid >= 8 * 640 * 320) return;
  const int k = gid % 320, j = (gid / 320) % 640, s = gid / (320 * 640);
  const int l = s >> 2, net = (s >> 1) & 1, dir = s & 1;
  float v = 0.f;
  if (j < G4 && k < NC) {
    const float* src = (net ? wu : wv) + (size_t)(l * 2 + dir) * (G4 * NC);
    v = src[(size_t)j * NC + k];
  }
  dst[gid] = __float2half(v);
}

// X fp32 [rows][300] -> Xh fp16 [rows][320] zero-padded
__global__ void conv_x(const float* __restrict__ src, __half* __restrict__ dst, int rows)
{
  const int gid = blockIdx.x * 256 + threadIdx.x;
  if (gid >= rows * 320) return;
  const int k = gid % 320, m = gid / 320;
  dst[gid] = __float2half(k < NC ? src[(size_t)m * NC + k] : 0.f);
}

// X fp32 [4096][300] -> XT fp16 [320][4096] (rows >= 300 zeroed)
__global__ void conv_t(const float* __restrict__ src, __half* __restrict__ dst)
{
  const int gid = blockIdx.x * 256 + threadIdx.x;
  if (gid >= 320 * 4096) return;
  const int m = gid % 4096, f = gid / 4096;
  dst[gid] = __float2half(f < NC ? src[(size_t)m * NC + f] : 0.f);
}

__global__ void zero_f(float* __restrict__ p, int n) {
  const int i = blockIdx.x * 256 + threadIdx.x;
  if (i < n) p[i] = 0.f;
}

// ---------------- xg = X @ Wih^T + b via fp16 MFMA -----------------------------
// grid (64 m-blocks, 4 chains), block 256 (4 waves, 16 rows each). N=640, K=320.
__global__ __launch_bounds__(256) void xg_mfma(
    const __half* __restrict__ Av, const __half* __restrict__ Au,
    const __half* __restrict__ W,   // Wihh + layer*4*640*320
    const float* __restrict__ bihv, const float* __restrict__ bhhv,
    const float* __restrict__ bihu, const float* __restrict__ bhhu,
    float* __restrict__ xg, int layer)
{
  const int tid = threadIdx.x;
  const int lane = tid & 63, wv = tid >> 6;
  const int ln = lane & 15, q = lane >> 4;
  const int chain = blockIdx.y;
  const __half* A = (chain >= 2) ? Au : Av;
  const __half* Wc = W + (size_t)chain * 640 * 320;
  const float* bi = ((chain >= 2) ? bihu : bihv) + (size_t)(layer * 2 + (chain & 1)) * G4;
  const float* bh = ((chain >= 2) ? bhhu : bhhv) + (size_t)(layer * 2 + (chain & 1)) * G4;
  float* C = xg + (size_t)chain * T_LEN * G4;
  const int m0 = blockIdx.x * 64 + wv * 16;
  const __half* Arow = A + (size_t)(m0 + ln) * 320;

  for (int nc = 0; nc < 4; nc++) {       // 4 chunks x 160 cols
    f32x4 acc[10];
#pragma unroll
    for (int j = 0; j < 10; j++) acc[j] = (f32x4){0.f, 0.f, 0.f, 0.f};
    for (int kk = 0; kk < 10; kk++) {
      const f16x8 afr = *(const f16x8*)(Arow + kk * 32 + q * 8);
#pragma unroll
      for (int j = 0; j < 10; j++) {
        const int n = nc * 160 + j * 16 + ln;
        const f16x8 bfr = *(const f16x8*)(Wc + (size_t)n * 320 + kk * 32 + q * 8);
        acc[j] = __builtin_amdgcn_mfma_f32_16x16x32_f16(afr, bfr, acc[j], 0, 0, 0);
      }
    }
#pragma unroll
    for (int j = 0; j < 10; j++) {
      const int n = nc * 160 + j * 16 + ln;
      if (n < G4) {
        const float bias = bi[n] + bh[n];
#pragma unroll
        for (int r = 0; r < 4; r++)
          C[(size_t)(m0 + q * 4 + r) * G4 + n] = acc[j][r] + bias;
      }
    }
  }
}

// ------- attention pass 1: sums[m] = sum_n exp(S[m][n] - 30), S = Hh @ Gh^T ----
// grid (64 m-blocks, 4 n-quadrants), block 256. Softmax is shift-invariant: a
// global constant shift replaces per-row max machinery (clamp = overflow guard).
__global__ __launch_bounds__(256) void s_pass1(
    const __half* __restrict__ Hh, const __half* __restrict__ Gh,
    float* __restrict__ sums)
{
  const int tid = threadIdx.x;
  const int lane = tid & 63, wv = tid >> 6;
  const int ln = lane & 15, q = lane >> 4;
  const int m0 = blockIdx.x * 64 + wv * 16;
  const __half* Arow = Hh + (size_t)(m0 + ln) * 320;
  f16x8 afr[10];
#pragma unroll
  for (int kk = 0; kk < 10; kk++) afr[kk] = *(const f16x8*)(Arow + kk * 32 + q * 8);
  float rs[4] = {0.f, 0.f, 0.f, 0.f};
  const int nt0 = blockIdx.y * 64;
  for (int nt = 0; nt < 64; nt++) {
    const __half* Brow = Gh + (size_t)(16 * (nt0 + nt) + ln) * 320;
    f32x4 acc = (f32x4){0.f, 0.f, 0.f, 0.f};
#pragma unroll
    for (int kk = 0; kk < 10; kk++) {
      const f16x8 bfr = *(const f16x8*)(Brow + kk * 32 + q * 8);
      acc = __builtin_amdgcn_mfma_f32_16x16x32_f16(afr[kk], bfr, acc, 0, 0, 0);
    }
#pragma unroll
    for (int r = 0; r < 4; r++) rs[r] += __expf(fminf(acc[r] - 30.f, 80.f));
  }
#pragma unroll
  for (int m = 1; m <= 8; m <<= 1)
#pragma unroll
    for (int r = 0; r < 4; r++) rs[r] += __shfl_xor(rs[r], m);
  if (ln == 0) {
#pragma unroll
    for (int r = 0; r < 4; r++) atomicAdd(&sums[m0 + q * 4 + r], rs[r]);
  }
}

__global__ void invert_k(const float* __restrict__ sums, float* __restrict__ il) {
  const int i = blockIdx.x * 256 + threadIdx.x;
  if (i < 4096) il[i] = 1.f / sums[i];
}

// ------- attention pass 2: a = exp(S-30)*il[m] -> AH fp16 (row-major only) -----
__global__ __launch_bounds__(256) void s_pass2(
    const __half* __restrict__ Hh, const __half* __restrict__ Gh,
    const float* __restrict__ il, __half* __restrict__ AH)
{
  const int tid = threadIdx.x;
  const int lane = tid & 63, wv = tid >> 6;
  const int ln = lane & 15, q = lane >> 4;
  const int m0 = blockIdx.x * 64 + wv * 16;
  const __half* Arow = Hh + (size_t)(m0 + ln) * 320;
  f16x8 afr[10];
#pragma unroll
  for (int kk = 0; kk < 10; kk++) afr[kk] = *(const f16x8*)(Arow + kk * 32 + q * 8);
  float ilr[4];
#pragma unroll
  for (int r = 0; r < 4; r++) ilr[r] = il[m0 + q * 4 + r];
  const int nt0 = blockIdx.y * 64;
  for (int nt = 0; nt < 64; nt++) {
    const int n = 16 * (nt0 + nt) + ln;
    const __half* Brow = Gh + (size_t)n * 320;
    f32x4 acc = (f32x4){0.f, 0.f, 0.f, 0.f};
#pragma unroll
    for (int kk = 0; kk < 10; kk++) {
      const f16x8 bfr = *(const f16x8*)(Brow + kk * 32 + q * 8);
      acc = __builtin_amdgcn_mfma_f32_16x16x32_f16(afr[kk], bfr, acc, 0, 0, 0);
    }
#pragma unroll
    for (int r = 0; r < 4; r++) {
      const float a = __expf(fminf(acc[r] - 30.f, 80.f)) * ilr[r];
      AH[(size_t)(m0 + q * 4 + r) * 4096 + n] = __float2half(a);
    }
  }
}

// ------- P = AH @ GhT' : M=4096, N=320(store 300), K=4096; A read row-major ----
__global__ __launch_bounds__(256) void p_mfma(
    const __half* __restrict__ AH, const __half* __restrict__ GhT,
    float* __restrict__ Pb)
{
  const int tid = threadIdx.x;
  const int lane = tid & 63, wv = tid >> 6;
  const int ln = lane & 15, q = lane >> 4;
  const int m0 = blockIdx.x * 64 + wv * 16;
  const __half* Arow = AH + (size_t)(m0 + ln) * 4096;

  for (int nc = 0; nc < 2; nc++) {
    f32x4 acc[10];
#pragma unroll
    for (int j = 0; j < 10; j++) acc[j] = (f32x4){0.f, 0.f, 0.f, 0.f};
    for (int kk = 0; kk < 128; kk++) {
      const f16x8 afr = *(const f16x8*)(Arow + kk * 32 + q * 8);
#pragma unroll
      for (int j = 0; j < 10; j++) {
        const int n = nc * 160 + j * 16 + ln;
        const f16x8 bfr = *(const f16x8*)(GhT + (size_t)n * 4096 + kk * 32 + q * 8);
        acc[j] = __builtin_amdgcn_mfma_f32_16x16x32_f16(afr, bfr, acc[j], 0, 0, 0);
      }
    }
#pragma unroll
    for (int j = 0; j < 10; j++) {
      const int n = nc * 160 + j * 16 + ln;
      if (n < NC) {
#pragma unroll
        for (int r = 0; r < 4; r++)
          Pb[(size_t)(m0 + q * 4 + r) * NC + n] = acc[j][r];
      }
    }
  }
}

// ------- Q[j][f] = sum_i a[i][j] H[i][f]: a-operand transposed via LDS ---------
// grid 64 (j-blocks of 64), block 256 (4 waves, 16 j-rows each). K=4096 in 64-chunks.
__global__ __launch_bounds__(256) void qt_mfma(
    const __half* __restrict__ AH, const __half* __restrict__ HhT,
    float* __restrict__ Qb)
{
  __shared__ __align__(16) _Float16 Ats[64][72];  // [j-local][i-local], pitch 144 B
  const int tid = threadIdx.x;
  const int lane = tid & 63, wv = tid >> 6;
  const int ln = lane & 15, q = lane >> 4;
  const int j0 = blockIdx.x * 64;
  f32x4 acc[20];
#pragma unroll
  for (int j = 0; j < 20; j++) acc[j] = (f32x4){0.f, 0.f, 0.f, 0.f};
  const int il8 = tid >> 2, j8 = (tid & 3) * 16;  // staging role

  for (int ic = 0; ic < 4096; ic += 64) {
    __syncthreads();  // protect LDS tile reuse
    {
      const __half* src = AH + (size_t)(ic + il8) * 4096 + j0 + j8;
      const f16x8 v0 = *(const f16x8*)src;
      const f16x8 v1 = *(const f16x8*)(src + 8);
#pragma unroll
      for (int jj = 0; jj < 8; jj++) Ats[j8 + jj][il8] = v0[jj];
#pragma unroll
      for (int jj = 0; jj < 8; jj++) Ats[j8 + 8 + jj][il8] = v1[jj];
    }
    __syncthreads();
#pragma unroll
    for (int s = 0; s < 2; s++) {
      const f16x8 afr = *(const f16x8*)&Ats[wv * 16 + ln][s * 32 + q * 8];
      const __half* bbase = HhT + ic + s * 32 + q * 8;
#pragma unroll
      for (int j = 0; j < 20; j++) {
        const f16x8 bfr = *(const f16x8*)(bbase + (size_t)(j * 16 + ln) * 4096);
        acc[j] = __builtin_amdgcn_mfma_f32_16x16x32_f16(afr, bfr, acc[j], 0, 0, 0);
      }
    }
  }
#pragma unroll
  for (int j = 0; j < 20; j++) {
    const int f = j * 16 + ln;
    if (f < NC) {
#pragma unroll
      for (int r = 0; r < 4; r++)
        Qb[(size_t)(j0 + wv * 16 + q * 4 + r) * NC + f] = acc[j][r];
    }
  }
}

// ---------------- tail ---------------------------------------------------------
__global__ void reduce_uv(const float* __restrict__ X, const float* __restrict__ Yp,
                          float* __restrict__ inp, int off)
{
  const int j = threadIdx.x;
  if (j >= NC) return;
  const int r0 = blockIdx.x * 128;
  float s = 0.f;
  for (int r = r0; r < r0 + 128; r++)
    s += fmaxf(X[(size_t)r * NC + j], Yp[(size_t)r * NC + j]);
  atomicAdd(&inp[off + j], s);
}

__global__ void fc1_k(const float* __restrict__ w1, const float* __restrict__ b1,
                      const float* __restrict__ inp, float* __restrict__ x)
{
  const int r = blockIdx.x * 256 + threadIdx.x;
  if (r >= 2000) return;
  float s = b1[r];
  const float* wr = w1 + (size_t)r * 600;
  for (int k = 0; k < 600; k++) s += wr[k] * inp[k];
  x[r] = fmaxf(s, 0.f);
}

__global__ void fc2_k(const float* __restrict__ x, const float* __restrict__ w2,
                      const float* __restrict__ b2, float* __restrict__ outp)
{
  const int tid = threadIdx.x;
  float s = 0.f;
  for (int i = tid; i < 2000; i += 256) s += x[i] * w2[i];
#pragma unroll
  for (int off = 32; off > 0; off >>= 1) s += __shfl_down(s, off);
  __shared__ float red[4];
  if ((tid & 63) == 0) red[tid >> 6] = s;
  __syncthreads();
  if (tid == 0) outp[0] = red[0] + red[1] + red[2] + red[3] + b2[0];
}

// ---------------- launch --------------------------------------------------------
extern "C" void kernel_launch(void* const* d_in, const int* in_sizes, int n_in,
                              void* d_out, int out_size, void* d_ws, size_t ws_size,
                              hipStream_t stream)
{
  const float* in_solv  = (const float*)d_in[0];
  const float* in_solu  = (const float*)d_in[1];
  const float* solv_Wih = (const float*)d_in[2];
  const float* solv_Whh = (const float*)d_in[3];
  const float* solv_bih = (const float*)d_in[4];
  const float* solv_bhh = (const float*)d_in[5];
  const float* solu_Wih = (const float*)d_in[6];
  const float* solu_Whh = (const float*)d_in[7];
  const float* solu_bih = (const float*)d_in[8];
  const float* solu_bhh = (const float*)d_in[9];
  const float* fc1_w = (const float*)d_in[10];
  const float* fc1_b = (const float*)d_in[11];
  const float* fc2_w = (const float*)d_in[12];
  const float* fc2_b = (const float*)d_in[13];
  float* outp = (float*)d_out;
  float* ws = (float*)d_ws;

  // ---- workspace layout (float offsets); peak 17,214,080 fl = 68.9 MB ----
  constexpr size_t off_P   = 0;          // Wihh (819,200 fl) early; P fp32 late
  constexpr size_t off_Q   = 1228800;    // Q fp32
  constexpr size_t off_inp = 2457600;    // 640
  constexpr size_t off_x   = 2458240;    // 2048
  constexpr size_t off_il  = 2460288;    // 4096
  constexpr size_t off_sm  = 2464384;    // 4096 (exp sums)
  constexpr size_t off_xg  = 2468480;    // xg 9,830,400 fl; later AH+HhT/GhT
  constexpr size_t off_L0  = off_xg + (size_t)4 * 2457600;   // L0v/L0u; Avh/Auh; Hh/Gh
  constexpr size_t off_HG  = off_L0 + (size_t)2 * 1228800;   // Hb/Gb; L0vh/L0uh transient

  float*  xg   = ws + off_xg;
  float*  L0v  = ws + off_L0;
  float*  L0u  = L0v + 1228800;
  float*  Hb   = ws + off_HG;
  float*  Gb   = Hb + 1228800;
  float*  Pb   = ws + off_P;
  float*  Qb   = ws + off_Q;
  float*  inp  = ws + off_inp;
  float*  xf   = ws + off_x;
  float*  il   = ws + off_il;
  float*  sums = ws + off_sm;
  __half* Wihh = (__half*)(ws + off_P);            // dead before P written
  __half* Avh  = (__half*)(ws + off_L0);           // dead before L0 written
  __half* Auh  = Avh + 4096 * 320;
  __half* L0vh = (__half*)(ws + off_HG);           // dead before Hb/Gb written
  __half* L0uh = L0vh + 4096 * 320;
  __half* Hh   = (__half*)(ws + off_L0);           // post-scan2 (L0 dead)
  __half* Gh   = Hh + 4096 * 320;
  __half* AH   = (__half*)(ws + off_xg);           // post-scan2 (xg dead)
  __half* HhT  = AH + (size_t)4096 * 4096;
  __half* GhT  = HhT + 320 * 4096;                 // total 9,699,328 < 9,830,400 ok

  // ---- weights + layer-0 inputs to fp16 ----
  conv_w<<<(8 * 640 * 320 + 255) / 256, 256, 0, stream>>>(solv_Wih, solu_Wih, Wihh);
  conv_x<<<(4096 * 320 + 255) / 256, 256, 0, stream>>>(in_solv, Avh, 4096);
  conv_x<<<(4096 * 320 + 255) / 256, 256, 0, stream>>>(in_solu, Auh, 4096);

  // ---- layer 0 ----
  xg_mfma<<<dim3(64, 4), 256, 0, stream>>>(Avh, Auh, Wihh,
      solv_bih, solv_bhh, solu_bih, solu_bhh, xg, 0);
  lstm_scan<<<4, 1024, 0, stream>>>(solv_Whh, solu_Whh, xg, L0v, L0u, 0);

  // ---- layer 1 ----
  conv_x<<<(4096 * 320 + 255) / 256, 256, 0, stream>>>(L0v, L0vh, 4096);
  conv_x<<<(4096 * 320 + 255) / 256, 256, 0, stream>>>(L0u, L0uh, 4096);
  xg_mfma<<<dim3(64, 4), 256, 0, stream>>>(L0vh, L0uh, Wihh + (size_t)4 * 640 * 320,
      solv_bih, solv_bhh, solu_bih, solu_bhh, xg, 1);
  lstm_scan<<<4, 1024, 0, stream>>>(solv_Whh, solu_Whh, xg, Hb, Gb, 1);

  // ---- attention (xg dead from here; AH/HhT/GhT live in its region) ----
  conv_x<<<(4096 * 320 + 255) / 256, 256, 0, stream>>>(Hb, Hh, 4096);
  conv_x<<<(4096 * 320 + 255) / 256, 256, 0, stream>>>(Gb, Gh, 4096);
  conv_t<<<(320 * 4096 + 255) / 256, 256, 0, stream>>>(Hb, HhT);
  conv_t<<<(320 * 4096 + 255) / 256, 256, 0, stream>>>(Gb, GhT);
  zero_f<<<16, 256, 0, stream>>>(sums, 4096);
  s_pass1<<<dim3(64, 4), 256, 0, stream>>>(Hh, Gh, sums);
  invert_k<<<16, 256, 0, stream>>>(sums, il);
  s_pass2<<<dim3(64, 4), 256, 0, stream>>>(Hh, Gh, il, AH);
  p_mfma<<<64, 256, 0, stream>>>(AH, GhT, Pb);
  qt_mfma<<<64, 256, 0, stream>>>(AH, HhT, Qb);

  // ---- tail ----
  zero_f<<<3, 256, 0, stream>>>(inp, 640);
  reduce_uv<<<32, 320, 0, stream>>>(Hb, Pb, inp, 0);
  reduce_uv<<<32, 320, 0, stream>>>(Gb, Qb, inp, 300);
  fc1_k<<<8, 256, 0, stream>>>(fc1_w, fc1_b, inp, xf);
  fc2_k<<<1, 256, 0, stream>>>(xf, fc2_w, fc2_b, outp);
}

// Round 8
// 7783.982 us; speedup vs baseline: 1.2183x; 1.0454x over previous
//
#include <hip/hip_runtime.h>
#include <hip/hip_fp16.h>
#include <cstddef>

#define T_LEN 4096
#define HID 150
#define G4 600
#define NC 300

typedef __attribute__((ext_vector_type(8))) short bf16x8;      // 8 bf16 = 4 VGPRs
typedef __attribute__((ext_vector_type(8))) _Float16 f16x8;    // 8 fp16 = 4 VGPRs
typedef __attribute__((ext_vector_type(4))) float f32x4;

// raw barrier: waits LDS ops only, leaves global loads/stores in flight
__device__ __forceinline__ void barrier_lgkm() {
  asm volatile("s_waitcnt lgkmcnt(0)\n\ts_barrier" ::: "memory");
}

__device__ __forceinline__ float fsig(float x) {
  return __builtin_amdgcn_rcpf(1.f + __expf(-x));
}
__device__ __forceinline__ float ftanh(float x) {
  float ax = fabsf(x);
  float e = __expf(2.f * ax);
  float t = 1.f - 2.f * __builtin_amdgcn_rcpf(e + 1.f);
  return copysignf(t, x);
}
__device__ __forceinline__ unsigned short f2bf(float f) {  // RNE fp32->bf16
  unsigned u = __builtin_bit_cast(unsigned, f);
  u += 0x7fff + ((u >> 16) & 1);
  return (unsigned short)(u >> 16);
}

// ---------------- LSTM scan, single-barrier MFMA form --------------------------
// 4 chains, one block (10 waves) each. Channels padded 150->160 so the gate
// vector is 640 = 4 gates x 160. Wave w owns the 4 gate-tiles of channel group
// w: tiles {w, w+10, w+20, w+30}. After its OWN 20 MFMAs, lane l<16 of wave w
// holds all 4 gates of channel 16w+l in acc[0..3][0] -> gate math is
// lane-local (no g_s scatter, no shfl). h double-buffered in LDS -> ONE
// barrier per step. MFMA pipe/SIMD worst-case ~1164 cyc (3 waves on 2 SIMDs),
// traded for deleting the ~600-cyc scatter/second-barrier serial phase.
__global__ __launch_bounds__(640, 3) void lstm_scan(
    const float* __restrict__ whh_solv, const float* __restrict__ whh_solu,
    const float* __restrict__ xg_base,
    float* __restrict__ out_solv, float* __restrict__ out_solu, int layer)
{
  __shared__ __align__(16) unsigned short hb[2][160];  // bf16 h, double-buffered
  const int c = blockIdx.x;
  const int net = c >> 1, dir = c & 1;
  const float* Whh = (net ? whh_solu : whh_solv) + (size_t)(layer * 2 + dir) * (G4 * HID);
  const float* xg = xg_base + (size_t)c * T_LEN * G4;
  float* out = (net ? out_solu : out_solv) + dir * HID;  // row stride NC
  const int tid = threadIdx.x;
  const int lane = tid & 63, wv = tid >> 6;   // wv 0..9
  const int lrow = lane & 15, lq = lane >> 4; // frag row & k-quad
  const bool gl = (lane < 16) && (16 * wv + lane < HID);  // gate lane
  const int ch = 16 * wv + lane;              // channel (valid when gl)

  // B-fragments: B[k][n] = Whh[gate j, channel 16w+lrow][k]
  bf16x8 bfr[4][5];  // [gate j][kk]
  {
    const int cc = 16 * wv + lrow;
    const bool cv = (cc < HID);
#pragma unroll
    for (int j = 0; j < 4; j++) {
      const size_t row = (size_t)(j * HID + cc) * HID;
#pragma unroll
      for (int kk = 0; kk < 5; kk++) {
        bf16x8 b;
#pragma unroll
        for (int i = 0; i < 8; i++) {
          const int k = kk * 32 + lq * 8 + i;
          const float v = (cv && k < HID) ? Whh[row + k] : 0.f;
          b[i] = (short)f2bf(v);
        }
        bfr[j][kk] = b;
      }
    }
  }
  if (tid < 160) { hb[0][tid] = 0; hb[1][tid] = 0; }
  float cst = 0.f;
  float xr0 = 0.f, xr1 = 0.f, xr2 = 0.f, xr3 = 0.f;
  if (gl) {
    const int t0 = dir ? (T_LEN - 1) : 0;
    const float* xgr = xg + (size_t)t0 * G4 + ch;
    xr0 = xgr[0]; xr1 = xgr[HID]; xr2 = xgr[2 * HID]; xr3 = xgr[3 * HID];
  }
  const f32x4 z4 = {0.f, 0.f, 0.f, 0.f};
  barrier_lgkm();

  int p = 0;
  for (int s = 0; s < T_LEN; s++) {
    const int t = dir ? (T_LEN - 1 - s) : s;
    // A-frags: row0 = h, rows 1-15 zero (rebuilt each step, r3 style)
    bf16x8 af[5];
#pragma unroll
    for (int kk = 0; kk < 5; kk++) {
      bf16x8 a = {0, 0, 0, 0, 0, 0, 0, 0};
      if (lrow == 0) a = *(const bf16x8*)&hb[p][kk * 32 + lq * 8];
      af[kk] = a;
    }
    f32x4 acc[4];
#pragma unroll
    for (int j = 0; j < 4; j++)
      acc[j] = __builtin_amdgcn_mfma_f32_16x16x32_bf16(af[0], bfr[j][0], z4, 0, 0, 0);
#pragma unroll
    for (int kk = 1; kk < 5; kk++)
#pragma unroll
      for (int j = 0; j < 4; j++)
        acc[j] = __builtin_amdgcn_mfma_f32_16x16x32_bf16(af[kk], bfr[j][kk], acc[j], 0, 0, 0);
    // gates: lane-local (D row0 = lanes 0-15, reg 0)
    if (gl) {
      const float gi = xr0 + acc[0][0];
      const float gf = xr1 + acc[1][0];
      const float gg = xr2 + acc[2][0];
      const float go = xr3 + acc[3][0];
      if (s + 1 < T_LEN) {  // prefetch next xg (stays in flight past barrier)
        const int tn = dir ? (T_LEN - 2 - s) : (s + 1);
        const float* xgr = xg + (size_t)tn * G4 + ch;
        xr0 = xgr[0]; xr1 = xgr[HID]; xr2 = xgr[2 * HID]; xr3 = xgr[3 * HID];
      }
      cst = fsig(gf) * cst + fsig(gi) * ftanh(gg);
      const float hv = fsig(go) * ftanh(cst);
      hb[1 - p][ch] = f2bf(hv);   // pad channels 150-159 stay 0 forever
      out[(size_t)t * NC + ch] = hv;
    }
    p ^= 1;
    barrier_lgkm();
  }
}

// ---------------- fp32 -> fp16 conversion helpers ------------------------------
// Wihh[8][640][320]: slot s = l*4 + net*2 + dir, zero-padded rows/cols
__global__ void conv_w(const float* __restrict__ wv, const float* __restrict__ wu,
                       __half* __restrict__ dst)
{
  const int gid = blockIdx.x * 256 + threadIdx.x;
  if (gid >= 8 * 640 * 320) return;
  const int k = gid % 320, j = (gid / 320) % 640, s = gid / (320 * 640);
  const int l = s >> 2, net = (s >> 1) & 1, dir = s & 1;
  float v = 0.f;
  if (j < G4 && k < NC) {
    const float* src = (net ? wu : wv) + (size_t)(l * 2 + dir) * (G4 * NC);
    v = src[(size_t)j * NC + k];
  }
  dst[gid] = __float2half(v);
}

// X fp32 [rows][300] -> Xh fp16 [rows][320] zero-padded
__global__ void conv_x(const float* __restrict__ src, __half* __restrict__ dst, int rows)
{
  const int gid = blockIdx.x * 256 + threadIdx.x;
  if (gid >= rows * 320) return;
  const int k = gid % 320, m = gid / 320;
  dst[gid] = __float2half(k < NC ? src[(size_t)m * NC + k] : 0.f);
}

// X fp32 [4096][300] -> XT fp16 [320][4096] (rows >= 300 zeroed)
__global__ void conv_t(const float* __restrict__ src, __half* __restrict__ dst)
{
  const int gid = blockIdx.x * 256 + threadIdx.x;
  if (gid >= 320 * 4096) return;
  const int m = gid % 4096, f = gid / 4096;
  dst[gid] = __float2half(f < NC ? src[(size_t)m * NC + f] : 0.f);
}

__global__ void zero_f(float* __restrict__ p, int n) {
  const int i = blockIdx.x * 256 + threadIdx.x;
  if (i < n) p[i] = 0.f;
}

// ---------------- xg = X @ Wih^T + b via fp16 MFMA -----------------------------
// grid (64 m-blocks, 4 chains), block 256 (4 waves, 16 rows each). N=640, K=320.
__global__ __launch_bounds__(256) void xg_mfma(
    const __half* __restrict__ Av, const __half* __restrict__ Au,
    const __half* __restrict__ W,   // Wihh + layer*4*640*320
    const float* __restrict__ bihv, const float* __restrict__ bhhv,
    const float* __restrict__ bihu, const float* __restrict__ bhhu,
    float* __restrict__ xg, int layer)
{
  const int tid = threadIdx.x;
  const int lane = tid & 63, wv = tid >> 6;
  const int ln = lane & 15, q = lane >> 4;
  const int chain = blockIdx.y;
  const __half* A = (chain >= 2) ? Au : Av;
  const __half* Wc = W + (size_t)chain * 640 * 320;
  const float* bi = ((chain >= 2) ? bihu : bihv) + (size_t)(layer * 2 + (chain & 1)) * G4;
  const float* bh = ((chain >= 2) ? bhhu : bhhv) + (size_t)(layer * 2 + (chain & 1)) * G4;
  float* C = xg + (size_t)chain * T_LEN * G4;
  const int m0 = blockIdx.x * 64 + wv * 16;
  const __half* Arow = A + (size_t)(m0 + ln) * 320;

  for (int nc = 0; nc < 4; nc++) {       // 4 chunks x 160 cols
    f32x4 acc[10];
#pragma unroll
    for (int j = 0; j < 10; j++) acc[j] = (f32x4){0.f, 0.f, 0.f, 0.f};
    for (int kk = 0; kk < 10; kk++) {
      const f16x8 afr = *(const f16x8*)(Arow + kk * 32 + q * 8);
#pragma unroll
      for (int j = 0; j < 10; j++) {
        const int n = nc * 160 + j * 16 + ln;
        const f16x8 bfr = *(const f16x8*)(Wc + (size_t)n * 320 + kk * 32 + q * 8);
        acc[j] = __builtin_amdgcn_mfma_f32_16x16x32_f16(afr, bfr, acc[j], 0, 0, 0);
      }
    }
#pragma unroll
    for (int j = 0; j < 10; j++) {
      const int n = nc * 160 + j * 16 + ln;
      if (n < G4) {
        const float bias = bi[n] + bh[n];
#pragma unroll
        for (int r = 0; r < 4; r++)
          C[(size_t)(m0 + q * 4 + r) * G4 + n] = acc[j][r] + bias;
      }
    }
  }
}

// ------- attention pass 1: sums[m] = sum_n exp(S[m][n] - 30), S = Hh @ Gh^T ----
// grid (64 m-blocks, 4 n-quadrants), block 256. Softmax is shift-invariant: a
// global constant shift replaces per-row max machinery (clamp = overflow guard).
__global__ __launch_bounds__(256) void s_pass1(
    const __half* __restrict__ Hh, const __half* __restrict__ Gh,
    float* __restrict__ sums)
{
  const int tid = threadIdx.x;
  const int lane = tid & 63, wv = tid >> 6;
  const int ln = lane & 15, q = lane >> 4;
  const int m0 = blockIdx.x * 64 + wv * 16;
  const __half* Arow = Hh + (size_t)(m0 + ln) * 320;
  f16x8 afr[10];
#pragma unroll
  for (int kk = 0; kk < 10; kk++) afr[kk] = *(const f16x8*)(Arow + kk * 32 + q * 8);
  float rs[4] = {0.f, 0.f, 0.f, 0.f};
  const int nt0 = blockIdx.y * 64;
  for (int nt = 0; nt < 64; nt++) {
    const __half* Brow = Gh + (size_t)(16 * (nt0 + nt) + ln) * 320;
    f32x4 acc = (f32x4){0.f, 0.f, 0.f, 0.f};
#pragma unroll
    for (int kk = 0; kk < 10; kk++) {
      const f16x8 bfr = *(const f16x8*)(Brow + kk * 32 + q * 8);
      acc = __builtin_amdgcn_mfma_f32_16x16x32_f16(afr[kk], bfr, acc, 0, 0, 0);
    }
#pragma unroll
    for (int r = 0; r < 4; r++) rs[r] += __expf(fminf(acc[r] - 30.f, 80.f));
  }
#pragma unroll
  for (int m = 1; m <= 8; m <<= 1)
#pragma unroll
    for (int r = 0; r < 4; r++) rs[r] += __shfl_xor(rs[r], m);
  if (ln == 0) {
#pragma unroll
    for (int r = 0; r < 4; r++) atomicAdd(&sums[m0 + q * 4 + r], rs[r]);
  }
}

__global__ void invert_k(const float* __restrict__ sums, float* __restrict__ il) {
  const int i = blockIdx.x * 256 + threadIdx.x;
  if (i < 4096) il[i] = 1.f / sums[i];
}

// ------- attention pass 2: a = exp(S-30)*il[m] -> AH fp16 (row-major only) -----
__global__ __launch_bounds__(256) void s_pass2(
    const __half* __restrict__ Hh, const __half* __restrict__ Gh,
    const float* __restrict__ il, __half* __restrict__ AH)
{
  const int tid = threadIdx.x;
  const int lane = tid & 63, wv = tid >> 6;
  const int ln = lane & 15, q = lane >> 4;
  const int m0 = blockIdx.x * 64 + wv * 16;
  const __half* Arow = Hh + (size_t)(m0 + ln) * 320;
  f16x8 afr[10];
#pragma unroll
  for (int kk = 0; kk < 10; kk++) afr[kk] = *(const f16x8*)(Arow + kk * 32 + q * 8);
  float ilr[4];
#pragma unroll
  for (int r = 0; r < 4; r++) ilr[r] = il[m0 + q * 4 + r];
  const int nt0 = blockIdx.y * 64;
  for (int nt = 0; nt < 64; nt++) {
    const int n = 16 * (nt0 + nt) + ln;
    const __half* Brow = Gh + (size_t)n * 320;
    f32x4 acc = (f32x4){0.f, 0.f, 0.f, 0.f};
#pragma unroll
    for (int kk = 0; kk < 10; kk++) {
      const f16x8 bfr = *(const f16x8*)(Brow + kk * 32 + q * 8);
      acc = __builtin_amdgcn_mfma_f32_16x16x32_f16(afr[kk], bfr, acc, 0, 0, 0);
    }
#pragma unroll
    for (int r = 0; r < 4; r++) {
      const float a = __expf(fminf(acc[r] - 30.f, 80.f)) * ilr[r];
      AH[(size_t)(m0 + q * 4 + r) * 4096 + n] = __float2half(a);
    }
  }
}

// ------- P = AH @ GhT' : M=4096, N=320(store 300), K=4096; A read row-major ----
__global__ __launch_bounds__(256) void p_mfma(
    const __half* __restrict__ AH, const __half* __restrict__ GhT,
    float* __restrict__ Pb)
{
  const int tid = threadIdx.x;
  const int lane = tid & 63, wv = tid >> 6;
  const int ln = lane & 15, q = lane >> 4;
  const int m0 = blockIdx.x * 64 + wv * 16;
  const __half* Arow = AH + (size_t)(m0 + ln) * 4096;

  for (int nc = 0; nc < 2; nc++) {
    f32x4 acc[10];
#pragma unroll
    for (int j = 0; j < 10; j++) acc[j] = (f32x4){0.f, 0.f, 0.f, 0.f};
    for (int kk = 0; kk < 128; kk++) {
      const f16x8 afr = *(const f16x8*)(Arow + kk * 32 + q * 8);
#pragma unroll
      for (int j = 0; j < 10; j++) {
        const int n = nc * 160 + j * 16 + ln;
        const f16x8 bfr = *(const f16x8*)(GhT + (size_t)n * 4096 + kk * 32 + q * 8);
        acc[j] = __builtin_amdgcn_mfma_f32_16x16x32_f16(afr, bfr, acc[j], 0, 0, 0);
      }
    }
#pragma unroll
    for (int j = 0; j < 10; j++) {
      const int n = nc * 160 + j * 16 + ln;
      if (n < NC) {
#pragma unroll
        for (int r = 0; r < 4; r++)
          Pb[(size_t)(m0 + q * 4 + r) * NC + n] = acc[j][r];
      }
    }
  }
}

// ------- Q[j][f] = sum_i a[i][j] H[i][f]: a-operand transposed via LDS ---------
// grid 64 (j-blocks of 64), block 256 (4 waves, 16 j-rows each). K=4096 in 64-chunks.
__global__ __launch_bounds__(256) void qt_mfma(
    const __half* __restrict__ AH, const __half* __restrict__ HhT,
    float* __restrict__ Qb)
{
  __shared__ __align__(16) _Float16 Ats[64][72];  // [j-local][i-local], pitch 144 B
  const int tid = threadIdx.x;
  const int lane = tid & 63, wv = tid >> 6;
  const int ln = lane & 15, q = lane >> 4;
  const int j0 = blockIdx.x * 64;
  f32x4 acc[20];
#pragma unroll
  for (int j = 0; j < 20; j++) acc[j] = (f32x4){0.f, 0.f, 0.f, 0.f};
  const int il8 = tid >> 2, j8 = (tid & 3) * 16;  // staging role

  for (int ic = 0; ic < 4096; ic += 64) {
    __syncthreads();  // protect LDS tile reuse
    {
      const __half* src = AH + (size_t)(ic + il8) * 4096 + j0 + j8;
      const f16x8 v0 = *(const f16x8*)src;
      const f16x8 v1 = *(const f16x8*)(src + 8);
#pragma unroll
      for (int jj = 0; jj < 8; jj++) Ats[j8 + jj][il8] = v0[jj];
#pragma unroll
      for (int jj = 0; jj < 8; jj++) Ats[j8 + 8 + jj][il8] = v1[jj];
    }
    __syncthreads();
#pragma unroll
    for (int s = 0; s < 2; s++) {
      const f16x8 afr = *(const f16x8*)&Ats[wv * 16 + ln][s * 32 + q * 8];
      const __half* bbase = HhT + ic + s * 32 + q * 8;
#pragma unroll
      for (int j = 0; j < 20; j++) {
        const f16x8 bfr = *(const f16x8*)(bbase + (size_t)(j * 16 + ln) * 4096);
        acc[j] = __builtin_amdgcn_mfma_f32_16x16x32_f16(afr, bfr, acc[j], 0, 0, 0);
      }
    }
  }
#pragma unroll
  for (int j = 0; j < 20; j++) {
    const int f = j * 16 + ln;
    if (f < NC) {
#pragma unroll
      for (int r = 0; r < 4; r++)
        Qb[(size_t)(j0 + wv * 16 + q * 4 + r) * NC + f] = acc[j][r];
    }
  }
}

// ---------------- tail ---------------------------------------------------------
__global__ void reduce_uv(const float* __restrict__ X, const float* __restrict__ Yp,
                          float* __restrict__ inp, int off)
{
  const int j = threadIdx.x;
  if (j >= NC) return;
  const int r0 = blockIdx.x * 128;
  float s = 0.f;
  for (int r = r0; r < r0 + 128; r++)
    s += fmaxf(X[(size_t)r * NC + j], Yp[(size_t)r * NC + j]);
  atomicAdd(&inp[off + j], s);
}

__global__ void fc1_k(const float* __restrict__ w1, const float* __restrict__ b1,
                      const float* __restrict__ inp, float* __restrict__ x)
{
  const int r = blockIdx.x * 256 + threadIdx.x;
  if (r >= 2000) return;
  float s = b1[r];
  const float* wr = w1 + (size_t)r * 600;
  for (int k = 0; k < 600; k++) s += wr[k] * inp[k];
  x[r] = fmaxf(s, 0.f);
}

__global__ void fc2_k(const float* __restrict__ x, const float* __restrict__ w2,
                      const float* __restrict__ b2, float* __restrict__ outp)
{
  const int tid = threadIdx.x;
  float s = 0.f;
  for (int i = tid; i < 2000; i += 256) s += x[i] * w2[i];
#pragma unroll
  for (int off = 32; off > 0; off >>= 1) s += __shfl_down(s, off);
  __shared__ float red[4];
  if ((tid & 63) == 0) red[tid >> 6] = s;
  __syncthreads();
  if (tid == 0) outp[0] = red[0] + red[1] + red[2] + red[3] + b2[0];
}

// ---------------- launch --------------------------------------------------------
extern "C" void kernel_launch(void* const* d_in, const int* in_sizes, int n_in,
                              void* d_out, int out_size, void* d_ws, size_t ws_size,
                              hipStream_t stream)
{
  const float* in_solv  = (const float*)d_in[0];
  const float* in_solu  = (const float*)d_in[1];
  const float* solv_Wih = (const float*)d_in[2];
  const float* solv_Whh = (const float*)d_in[3];
  const float* solv_bih = (const float*)d_in[4];
  const float* solv_bhh = (const float*)d_in[5];
  const float* solu_Wih = (const float*)d_in[6];
  const float* solu_Whh = (const float*)d_in[7];
  const float* solu_bih = (const float*)d_in[8];
  const float* solu_bhh = (const float*)d_in[9];
  const float* fc1_w = (const float*)d_in[10];
  const float* fc1_b = (const float*)d_in[11];
  const float* fc2_w = (const float*)d_in[12];
  const float* fc2_b = (const float*)d_in[13];
  float* outp = (float*)d_out;
  float* ws = (float*)d_ws;

  // ---- workspace layout (float offsets); peak 17,214,080 fl = 68.9 MB ----
  constexpr size_t off_P   = 0;          // Wihh (819,200 fl) early; P fp32 late
  constexpr size_t off_Q   = 1228800;    // Q fp32
  constexpr size_t off_inp = 2457600;    // 640
  constexpr size_t off_x   = 2458240;    // 2048
  constexpr size_t off_il  = 2460288;    // 4096
  constexpr size_t off_sm  = 2464384;    // 4096 (exp sums)
  constexpr size_t off_xg  = 2468480;    // xg 9,830,400 fl; later AH+HhT/GhT
  constexpr size_t off_L0  = off_xg + (size_t)4 * 2457600;   // L0v/L0u; Avh/Auh; Hh/Gh
  constexpr size_t off_HG  = off_L0 + (size_t)2 * 1228800;   // Hb/Gb; L0vh/L0uh transient

  float*  xg   = ws + off_xg;
  float*  L0v  = ws + off_L0;
  float*  L0u  = L0v + 1228800;
  float*  Hb   = ws + off_HG;
  float*  Gb   = Hb + 1228800;
  float*  Pb   = ws + off_P;
  float*  Qb   = ws + off_Q;
  float*  inp  = ws + off_inp;
  float*  xf   = ws + off_x;
  float*  il   = ws + off_il;
  float*  sums = ws + off_sm;
  __half* Wihh = (__half*)(ws + off_P);            // dead before P written
  __half* Avh  = (__half*)(ws + off_L0);           // dead before L0 written
  __half* Auh  = Avh + 4096 * 320;
  __half* L0vh = (__half*)(ws + off_HG);           // dead before Hb/Gb written
  __half* L0uh = L0vh + 4096 * 320;
  __half* Hh   = (__half*)(ws + off_L0);           // post-scan2 (L0 dead)
  __half* Gh   = Hh + 4096 * 320;
  __half* AH   = (__half*)(ws + off_xg);           // post-scan2 (xg dead)
  __half* HhT  = AH + (size_t)4096 * 4096;
  __half* GhT  = HhT + 320 * 4096;                 // total 9,699,328 < 9,830,400 ok

  // ---- weights + layer-0 inputs to fp16 ----
  conv_w<<<(8 * 640 * 320 + 255) / 256, 256, 0, stream>>>(solv_Wih, solu_Wih, Wihh);
  conv_x<<<(4096 * 320 + 255) / 256, 256, 0, stream>>>(in_solv, Avh, 4096);
  conv_x<<<(4096 * 320 + 255) / 256, 256, 0, stream>>>(in_solu, Auh, 4096);

  // ---- layer 0 ----
  xg_mfma<<<dim3(64, 4), 256, 0, stream>>>(Avh, Auh, Wihh,
      solv_bih, solv_bhh, solu_bih, solu_bhh, xg, 0);
  lstm_scan<<<4, 640, 0, stream>>>(solv_Whh, solu_Whh, xg, L0v, L0u, 0);

  // ---- layer 1 ----
  conv_x<<<(4096 * 320 + 255) / 256, 256, 0, stream>>>(L0v, L0vh, 4096);
  conv_x<<<(4096 * 320 + 255) / 256, 256, 0, stream>>>(L0u, L0uh, 4096);
  xg_mfma<<<dim3(64, 4), 256, 0, stream>>>(L0vh, L0uh, Wihh + (size_t)4 * 640 * 320,
      solv_bih, solv_bhh, solu_bih, solu_bhh, xg, 1);
  lstm_scan<<<4, 640, 0, stream>>>(solv_Whh, solu_Whh, xg, Hb, Gb, 1);

  // ---- attention (xg dead from here; AH/HhT/GhT live in its region) ----
  conv_x<<<(4096 * 320 + 255) / 256, 256, 0, stream>>>(Hb, Hh, 4096);
  conv_x<<<(4096 * 320 + 255) / 256, 256, 0, stream>>>(Gb, Gh, 4096);
  conv_t<<<(320 * 4096 + 255) / 256, 256, 0, stream>>>(Hb, HhT);
  conv_t<<<(320 * 4096 + 255) / 256, 256, 0, stream>>>(Gb, GhT);
  zero_f<<<16, 256, 0, stream>>>(sums, 4096);
  s_pass1<<<dim3(64, 4), 256, 0, stream>>>(Hh, Gh, sums);
  invert_k<<<16, 256, 0, stream>>>(sums, il);
  s_pass2<<<dim3(64, 4), 256, 0, stream>>>(Hh, Gh, il, AH);
  p_mfma<<<64, 256, 0, stream>>>(AH, GhT, Pb);
  qt_mfma<<<64, 256, 0, stream>>>(AH, HhT, Qb);

  // ---- tail ----
  zero_f<<<3, 256, 0, stream>>>(inp, 640);
  reduce_uv<<<32, 320, 0, stream>>>(Hb, Pb, inp, 0);
  reduce_uv<<<32, 320, 0, stream>>>(Gb, Qb, inp, 300);
  fc1_k<<<8, 256, 0, stream>>>(fc1_w, fc1_b, inp, xf);
  fc2_k<<<1, 256, 0, stream>>>(xf, fc2_w, fc2_b, outp);
}

// Round 9
// 7062.553 us; speedup vs baseline: 1.3428x; 1.1021x over previous
//
#include <hip/hip_runtime.h>
#include <hip/hip_fp16.h>
#include <cstddef>

#define T_LEN 4096
#define HID 150
#define G4 600
#define NC 300

typedef __attribute__((ext_vector_type(8))) short bf16x8;      // 8 bf16 = 4 VGPRs
typedef __attribute__((ext_vector_type(8))) _Float16 f16x8;    // 8 fp16 = 4 VGPRs
typedef __attribute__((ext_vector_type(4))) float f32x4;

// raw barrier: waits LDS ops only, leaves global loads/stores in flight
__device__ __forceinline__ void barrier_lgkm() {
  asm volatile("s_waitcnt lgkmcnt(0)\n\ts_barrier" ::: "memory");
}

__device__ __forceinline__ float fsig(float x) {
  return __builtin_amdgcn_rcpf(1.f + __expf(-x));
}
__device__ __forceinline__ float ftanh(float x) {
  float ax = fabsf(x);
  float e = __expf(2.f * ax);
  float t = 1.f - 2.f * __builtin_amdgcn_rcpf(e + 1.f);
  return copysignf(t, x);
}
__device__ __forceinline__ unsigned short f2bf(float f) {  // RNE fp32->bf16
  unsigned u = __builtin_bit_cast(unsigned, f);
  u += 0x7fff + ((u >> 16) & 1);
  return (unsigned short)(u >> 16);
}

// ---------------- LSTM scan via MFMA: EXACT r3 structure (best measured: -------
// 1743 cyc/step) + fused fp16 padded output. 4 chains, one block (8 waves).
// g[640] = h[160] @ WhhT as 16x16x32 bf16 MFMA, A row0 = h, rows 1-15 = 0.
// DO NOT restructure: r5(af-hoist)/r6(gate-permute)/r7(16-wave)/r8(1-barrier)
// all measured slower (1854/2439/1968/1893 cyc).
__global__ __launch_bounds__(512, 2) void lstm_scan(
    const float* __restrict__ whh_solv, const float* __restrict__ whh_solu,
    const float* __restrict__ xg_base,
    float* __restrict__ o32v, float* __restrict__ o32u,
    __half* __restrict__ o16v, __half* __restrict__ o16u, int layer, int w32)
{
  __shared__ __align__(16) unsigned short h_bf[160];  // bf16 h, zeros beyond 150
  __shared__ float g_s[640];
  const int c = blockIdx.x;
  const int net = c >> 1, dir = c & 1;
  const float* Whh = (net ? whh_solu : whh_solv) + (size_t)(layer * 2 + dir) * (G4 * HID);
  const float* xg = xg_base + (size_t)c * T_LEN * G4;
  float* out32 = (net ? o32u : o32v) + dir * HID;     // row stride NC (if w32)
  __half* out16 = (net ? o16u : o16v) + dir * HID;    // row stride 320
  const int tid = threadIdx.x;
  const int lane = tid & 63, wv = tid >> 6;
  const int lrow = lane & 15, lq = lane >> 4;  // frag row & k-quad

  // B-fragments: B[k][n] = Whh[n][k]; lane holds n=16*tile+lrow, k=kk*32+lq*8+i
  bf16x8 bfr[5][5];  // [j][kk]
#pragma unroll
  for (int j = 0; j < 5; j++) {
    const int jrow = 16 * (wv + 8 * j) + lrow;
#pragma unroll
    for (int kk = 0; kk < 5; kk++) {
      bf16x8 b;
#pragma unroll
      for (int i = 0; i < 8; i++) {
        const int k = kk * 32 + lq * 8 + i;
        const float v = (jrow < G4 && k < HID) ? Whh[(size_t)jrow * HID + k] : 0.f;
        b[i] = (short)f2bf(v);
      }
      bfr[j][kk] = b;
    }
  }
  if (tid < 160) h_bf[tid] = 0;
  float cst = 0.f;
  float xr0 = 0.f, xr1 = 0.f, xr2 = 0.f, xr3 = 0.f;
  if (tid < HID) {
    const int t0 = dir ? (T_LEN - 1) : 0;
    const float* xgr = xg + (size_t)t0 * G4 + tid;
    xr0 = xgr[0]; xr1 = xgr[HID]; xr2 = xgr[2 * HID]; xr3 = xgr[3 * HID];
  }
  barrier_lgkm();

  for (int s = 0; s < T_LEN; s++) {
    const int t = dir ? (T_LEN - 1 - s) : s;
    // A-frags: row0 = h_bf, rows 1-15 zero -> only lanes with lrow==0 load
    bf16x8 af[5];
#pragma unroll
    for (int kk = 0; kk < 5; kk++) {
      bf16x8 a = {0, 0, 0, 0, 0, 0, 0, 0};
      if (lrow == 0) a = *(const bf16x8*)&h_bf[kk * 32 + lq * 8];
      af[kk] = a;
    }
    f32x4 acc[5];
#pragma unroll
    for (int j = 0; j < 5; j++) acc[j] = (f32x4){0.f, 0.f, 0.f, 0.f};
#pragma unroll
    for (int kk = 0; kk < 5; kk++)
#pragma unroll
      for (int j = 0; j < 5; j++)
        acc[j] = __builtin_amdgcn_mfma_f32_16x16x32_bf16(af[kk], bfr[j][kk], acc[j], 0, 0, 0);
    // D row0 lives in lanes 0-15, reg 0
    if (lane < 16) {
#pragma unroll
      for (int j = 0; j < 5; j++) g_s[16 * (wv + 8 * j) + lane] = acc[j][0];
    }
    barrier_lgkm();
    if (tid < HID) {
      const int n = tid;
      float gi = xr0 + g_s[n];
      float gf = xr1 + g_s[HID + n];
      float gg = xr2 + g_s[2 * HID + n];
      float go = xr3 + g_s[3 * HID + n];
      if (s + 1 < T_LEN) {  // prefetch next xg row (stays in flight past barrier)
        const int tn = dir ? (T_LEN - 2 - s) : (s + 1);
        const float* xgr = xg + (size_t)tn * G4 + n;
        xr0 = xgr[0]; xr1 = xgr[HID]; xr2 = xgr[2 * HID]; xr3 = xgr[3 * HID];
      }
      const float iv = fsig(gi), fv = fsig(gf), gv = ftanh(gg), ov = fsig(go);
      cst = fv * cst + iv * gv;
      const float hv = ov * ftanh(cst);
      h_bf[n] = f2bf(hv);      // matvec input rounded; c/h state stays fp32
      out16[(size_t)t * 320 + n] = __float2half(hv);
      if (w32) out32[(size_t)t * NC + n] = hv;
    }
    barrier_lgkm();
  }
}

// ---------------- fp32 -> fp16 conversion helpers ------------------------------
// Wihh[8][640][320]: slot s = l*4 + net*2 + dir, zero-padded rows/cols
__global__ void conv_w(const float* __restrict__ wv, const float* __restrict__ wu,
                       __half* __restrict__ dst)
{
  const int gid = blockIdx.x * 256 + threadIdx.x;
  if (gid >= 8 * 640 * 320) return;
  const int k = gid % 320, j = (gid / 320) % 640, s = gid / (320 * 640);
  const int l = s >> 2, net = (s >> 1) & 1, dir = s & 1;
  float v = 0.f;
  if (j < G4 && k < NC) {
    const float* src = (net ? wu : wv) + (size_t)(l * 2 + dir) * (G4 * NC);
    v = src[(size_t)j * NC + k];
  }
  dst[gid] = __float2half(v);
}

// X fp32 [rows][300] -> Xh fp16 [rows][320] zero-padded
__global__ void conv_x(const float* __restrict__ src, __half* __restrict__ dst, int rows)
{
  const int gid = blockIdx.x * 256 + threadIdx.x;
  if (gid >= rows * 320) return;
  const int k = gid % 320, m = gid / 320;
  dst[gid] = __float2half(k < NC ? src[(size_t)m * NC + k] : 0.f);
}

// X fp32 [4096][300] -> XT fp16 [320][4096] (rows >= 300 zeroed)
__global__ void conv_t(const float* __restrict__ src, __half* __restrict__ dst)
{
  const int gid = blockIdx.x * 256 + threadIdx.x;
  if (gid >= 320 * 4096) return;
  const int m = gid % 4096, f = gid / 4096;
  dst[gid] = __float2half(f < NC ? src[(size_t)m * NC + f] : 0.f);
}

__global__ void zero_f(float* __restrict__ p, int n) {
  const int i = blockIdx.x * 256 + threadIdx.x;
  if (i < n) p[i] = 0.f;
}

// ---------------- xg = X @ Wih^T + b via fp16 MFMA -----------------------------
// grid (64 m-blocks, 4 chains), block 256 (4 waves, 16 rows each). N=640, K=320.
__global__ __launch_bounds__(256) void xg_mfma(
    const __half* __restrict__ Av, const __half* __restrict__ Au,
    const __half* __restrict__ W,   // Wihh + layer*4*640*320
    const float* __restrict__ bihv, const float* __restrict__ bhhv,
    const float* __restrict__ bihu, const float* __restrict__ bhhu,
    float* __restrict__ xg, int layer)
{
  const int tid = threadIdx.x;
  const int lane = tid & 63, wv = tid >> 6;
  const int ln = lane & 15, q = lane >> 4;
  const int chain = blockIdx.y;
  const __half* A = (chain >= 2) ? Au : Av;
  const __half* Wc = W + (size_t)chain * 640 * 320;
  const float* bi = ((chain >= 2) ? bihu : bihv) + (size_t)(layer * 2 + (chain & 1)) * G4;
  const float* bh = ((chain >= 2) ? bhhu : bhhv) + (size_t)(layer * 2 + (chain & 1)) * G4;
  float* C = xg + (size_t)chain * T_LEN * G4;
  const int m0 = blockIdx.x * 64 + wv * 16;
  const __half* Arow = A + (size_t)(m0 + ln) * 320;

  for (int nc = 0; nc < 4; nc++) {       // 4 chunks x 160 cols
    f32x4 acc[10];
#pragma unroll
    for (int j = 0; j < 10; j++) acc[j] = (f32x4){0.f, 0.f, 0.f, 0.f};
    for (int kk = 0; kk < 10; kk++) {
      const f16x8 afr = *(const f16x8*)(Arow + kk * 32 + q * 8);
#pragma unroll
      for (int j = 0; j < 10; j++) {
        const int n = nc * 160 + j * 16 + ln;
        const f16x8 bfr = *(const f16x8*)(Wc + (size_t)n * 320 + kk * 32 + q * 8);
        acc[j] = __builtin_amdgcn_mfma_f32_16x16x32_f16(afr, bfr, acc[j], 0, 0, 0);
      }
    }
#pragma unroll
    for (int j = 0; j < 10; j++) {
      const int n = nc * 160 + j * 16 + ln;
      if (n < G4) {
        const float bias = bi[n] + bh[n];
#pragma unroll
        for (int r = 0; r < 4; r++)
          C[(size_t)(m0 + q * 4 + r) * G4 + n] = acc[j][r] + bias;
      }
    }
  }
}

// ------- S GEMM: AH[m][n] = fp16(Hh[m] . Gh[n]), raw scores (no exp) -----------
// grid (64 m-blocks, 4 n-quadrants), block 256. Softmax shift/normalization
// happens later on the ROUNDED values (self-consistent).
__global__ __launch_bounds__(256) void s_gemm(
    const __half* __restrict__ Hh, const __half* __restrict__ Gh,
    __half* __restrict__ AH)
{
  const int tid = threadIdx.x;
  const int lane = tid & 63, wv = tid >> 6;
  const int ln = lane & 15, q = lane >> 4;
  const int m0 = blockIdx.x * 64 + wv * 16;
  const __half* Arow = Hh + (size_t)(m0 + ln) * 320;
  f16x8 afr[10];
#pragma unroll
  for (int kk = 0; kk < 10; kk++) afr[kk] = *(const f16x8*)(Arow + kk * 32 + q * 8);
  const int nt0 = blockIdx.y * 64;
  for (int nt = 0; nt < 64; nt++) {
    const int n = 16 * (nt0 + nt) + ln;
    const __half* Brow = Gh + (size_t)n * 320;
    f32x4 acc = (f32x4){0.f, 0.f, 0.f, 0.f};
#pragma unroll
    for (int kk = 0; kk < 10; kk++) {
      const f16x8 bfr = *(const f16x8*)(Brow + kk * 32 + q * 8);
      acc = __builtin_amdgcn_mfma_f32_16x16x32_f16(afr[kk], bfr, acc, 0, 0, 0);
    }
#pragma unroll
    for (int r = 0; r < 4; r++)
      AH[(size_t)(m0 + q * 4 + r) * 4096 + n] = __float2half(acc[r]);
  }
}

// ------- rowsum: il[m] = 1 / sum_n exp(S[m][n] - 30)  (one block per row) ------
__global__ __launch_bounds__(256) void rowsum_k(const __half* __restrict__ AH,
                                                float* __restrict__ il)
{
  const int m = blockIdx.x, tid = threadIdx.x;
  const __half* row = AH + (size_t)m * 4096;
  float s = 0.f;
  for (int i = tid * 8; i < 4096; i += 2048) {
    const f16x8 v = *(const f16x8*)(row + i);
#pragma unroll
    for (int j = 0; j < 8; j++) s += __expf(fminf((float)v[j] - 30.f, 80.f));
  }
#pragma unroll
  for (int off = 32; off > 0; off >>= 1) s += __shfl_down(s, off);
  __shared__ float red[4];
  if ((tid & 63) == 0) red[tid >> 6] = s;
  __syncthreads();
  if (tid == 0) il[m] = 1.f / (red[0] + red[1] + red[2] + red[3]);
}

// ------- scale: AH = fp16( exp(S-30) * il[m] ), in place -----------------------
__global__ __launch_bounds__(256) void scale_k(__half* __restrict__ AH,
                                               const float* __restrict__ il)
{
  const size_t gid = (size_t)blockIdx.x * 256 + threadIdx.x;  // f16x8 chunk id
  const int m = (int)(gid >> 9);                              // 512 chunks/row
  const float ilm = il[m];
  f16x8 v = *(f16x8*)(AH + gid * 8);
#pragma unroll
  for (int j = 0; j < 8; j++)
    v[j] = (_Float16)(__expf(fminf((float)v[j] - 30.f, 80.f)) * ilm);
  *(f16x8*)(AH + gid * 8) = v;
}

// ------- P = AH @ GhT' and Q = AH^T @ HhT' in ONE dispatch (128 blocks) --------
__global__ __launch_bounds__(256) void pq_mfma(
    const __half* __restrict__ AH, const __half* __restrict__ GhT,
    const __half* __restrict__ HhT,
    float* __restrict__ Pb, float* __restrict__ Qb)
{
  __shared__ __align__(16) _Float16 Ats[64][72];  // qt staging, pitch 144 B
  const int tid = threadIdx.x;
  const int lane = tid & 63, wv = tid >> 6;
  const int ln = lane & 15, q = lane >> 4;

  if (blockIdx.x < 64) {
    // ---- P part: M=4096 rows of AH, N=320(store 300), K=4096 ----
    const int m0 = blockIdx.x * 64 + wv * 16;
    const __half* Arow = AH + (size_t)(m0 + ln) * 4096;
    for (int nc = 0; nc < 2; nc++) {
      f32x4 acc[10];
#pragma unroll
      for (int j = 0; j < 10; j++) acc[j] = (f32x4){0.f, 0.f, 0.f, 0.f};
      for (int kk = 0; kk < 128; kk++) {
        const f16x8 afr = *(const f16x8*)(Arow + kk * 32 + q * 8);
#pragma unroll
        for (int j = 0; j < 10; j++) {
          const int n = nc * 160 + j * 16 + ln;
          const f16x8 bfr = *(const f16x8*)(GhT + (size_t)n * 4096 + kk * 32 + q * 8);
          acc[j] = __builtin_amdgcn_mfma_f32_16x16x32_f16(afr, bfr, acc[j], 0, 0, 0);
        }
      }
#pragma unroll
      for (int j = 0; j < 10; j++) {
        const int n = nc * 160 + j * 16 + ln;
        if (n < NC) {
#pragma unroll
          for (int r = 0; r < 4; r++)
            Pb[(size_t)(m0 + q * 4 + r) * NC + n] = acc[j][r];
        }
      }
    }
  } else {
    // ---- Q part: Q[j][f] = sum_i a[i][j] H[i][f]; a transposed via LDS ----
    const int j0 = (blockIdx.x - 64) * 64;
    f32x4 acc[20];
#pragma unroll
    for (int j = 0; j < 20; j++) acc[j] = (f32x4){0.f, 0.f, 0.f, 0.f};
    const int il8 = tid >> 2, j8 = (tid & 3) * 16;  // staging role
    for (int ic = 0; ic < 4096; ic += 64) {
      __syncthreads();
      {
        const __half* src = AH + (size_t)(ic + il8) * 4096 + j0 + j8;
        const f16x8 v0 = *(const f16x8*)src;
        const f16x8 v1 = *(const f16x8*)(src + 8);
#pragma unroll
        for (int jj = 0; jj < 8; jj++) Ats[j8 + jj][il8] = v0[jj];
#pragma unroll
        for (int jj = 0; jj < 8; jj++) Ats[j8 + 8 + jj][il8] = v1[jj];
      }
      __syncthreads();
#pragma unroll
      for (int s = 0; s < 2; s++) {
        const f16x8 afr = *(const f16x8*)&Ats[wv * 16 + ln][s * 32 + q * 8];
        const __half* bbase = HhT + ic + s * 32 + q * 8;
#pragma unroll
        for (int j = 0; j < 20; j++) {
          const f16x8 bfr = *(const f16x8*)(bbase + (size_t)(j * 16 + ln) * 4096);
          acc[j] = __builtin_amdgcn_mfma_f32_16x16x32_f16(afr, bfr, acc[j], 0, 0, 0);
        }
      }
    }
#pragma unroll
    for (int j = 0; j < 20; j++) {
      const int f = j * 16 + ln;
      if (f < NC) {
#pragma unroll
        for (int r = 0; r < 4; r++)
          Qb[(size_t)(j0 + wv * 16 + q * 4 + r) * NC + f] = acc[j][r];
      }
    }
  }
}

// ---------------- tail ---------------------------------------------------------
__global__ void reduce_uv(const float* __restrict__ X, const float* __restrict__ Yp,
                          float* __restrict__ inp, int off)
{
  const int j = threadIdx.x;
  if (j >= NC) return;
  const int r0 = blockIdx.x * 128;
  float s = 0.f;
  for (int r = r0; r < r0 + 128; r++)
    s += fmaxf(X[(size_t)r * NC + j], Yp[(size_t)r * NC + j]);
  atomicAdd(&inp[off + j], s);
}

__global__ void fc1_k(const float* __restrict__ w1, const float* __restrict__ b1,
                      const float* __restrict__ inp, float* __restrict__ x)
{
  const int r = blockIdx.x * 256 + threadIdx.x;
  if (r >= 2000) return;
  float s = b1[r];
  const float* wr = w1 + (size_t)r * 600;
  for (int k = 0; k < 600; k++) s += wr[k] * inp[k];
  x[r] = fmaxf(s, 0.f);
}

__global__ void fc2_k(const float* __restrict__ x, const float* __restrict__ w2,
                      const float* __restrict__ b2, float* __restrict__ outp)
{
  const int tid = threadIdx.x;
  float s = 0.f;
  for (int i = tid; i < 2000; i += 256) s += x[i] * w2[i];
#pragma unroll
  for (int off = 32; off > 0; off >>= 1) s += __shfl_down(s, off);
  __shared__ float red[4];
  if ((tid & 63) == 0) red[tid >> 6] = s;
  __syncthreads();
  if (tid == 0) outp[0] = red[0] + red[1] + red[2] + red[3] + b2[0];
}

// ---------------- launch --------------------------------------------------------
extern "C" void kernel_launch(void* const* d_in, const int* in_sizes, int n_in,
                              void* d_out, int out_size, void* d_ws, size_t ws_size,
                              hipStream_t stream)
{
  const float* in_solv  = (const float*)d_in[0];
  const float* in_solu  = (const float*)d_in[1];
  const float* solv_Wih = (const float*)d_in[2];
  const float* solv_Whh = (const float*)d_in[3];
  const float* solv_bih = (const float*)d_in[4];
  const float* solv_bhh = (const float*)d_in[5];
  const float* solu_Wih = (const float*)d_in[6];
  const float* solu_Whh = (const float*)d_in[7];
  const float* solu_bih = (const float*)d_in[8];
  const float* solu_bhh = (const float*)d_in[9];
  const float* fc1_w = (const float*)d_in[10];
  const float* fc1_b = (const float*)d_in[11];
  const float* fc2_w = (const float*)d_in[12];
  const float* fc2_b = (const float*)d_in[13];
  float* outp = (float*)d_out;
  float* ws = (float*)d_ws;

  // ---- workspace layout (float offsets); peak 16,067,200 fl < prior 17.2M ----
  // off_P:  Wihh (819,200 fl) early -> Pb fp32 late (Wihh dead after xg_mfma l1)
  // off_xg: xg (9,830,400 fl) -> AH fp16 (8,388,608 fl) + HhT/GhT (655,360 fl)
  // off_L0: Avh/Auh fp16 -> Hh/Gh fp16 (pads inherited from conv_x zeros)
  // off_HG: L0vh/L0uh fp16 (pads pre-zeroed) -> Hb/Gb fp32 (after xg_mfma l1)
  constexpr size_t off_P   = 0;
  constexpr size_t off_Q   = 1228800;
  constexpr size_t off_inp = 2457600;   // 640
  constexpr size_t off_x   = 2458240;   // 2048
  constexpr size_t off_il  = 2460288;   // 4096
  constexpr size_t off_xg  = 2468480;
  constexpr size_t off_L0  = off_xg + (size_t)4 * 2457600;   // 12,298,880
  constexpr size_t off_HG  = off_L0 + 1310720;               // 13,609,600

  float*  xg   = ws + off_xg;
  float*  Hb   = ws + off_HG;
  float*  Gb   = Hb + 1228800;
  float*  Pb   = ws + off_P;
  float*  Qb   = ws + off_Q;
  float*  inp  = ws + off_inp;
  float*  xf   = ws + off_x;
  float*  il   = ws + off_il;
  __half* Wihh = (__half*)(ws + off_P);
  __half* Avh  = (__half*)(ws + off_L0);
  __half* Auh  = Avh + 4096 * 320;
  __half* L0vh = (__half*)(ws + off_HG);
  __half* L0uh = L0vh + 4096 * 320;
  __half* Hh   = (__half*)(ws + off_L0);   // reuses Avh/Auh space (dead)
  __half* Gh   = Hh + 4096 * 320;
  __half* AH   = (__half*)(ws + off_xg);   // after scans (xg dead)
  __half* HhT  = AH + (size_t)4096 * 4096;
  __half* GhT  = HhT + 320 * 4096;

  // ---- prep: zero L0vh/L0uh pads, convert weights + inputs to fp16 ----
  zero_f<<<5120, 256, 0, stream>>>(ws + off_HG, 1310720);
  conv_w<<<(8 * 640 * 320 + 255) / 256, 256, 0, stream>>>(solv_Wih, solu_Wih, Wihh);
  conv_x<<<5120, 256, 0, stream>>>(in_solv, Avh, 4096);
  conv_x<<<5120, 256, 0, stream>>>(in_solu, Auh, 4096);

  // ---- layer 0 (scan writes fp16 L0vh/L0uh directly; no fp32 out) ----
  xg_mfma<<<dim3(64, 4), 256, 0, stream>>>(Avh, Auh, Wihh,
      solv_bih, solv_bhh, solu_bih, solu_bhh, xg, 0);
  lstm_scan<<<4, 512, 0, stream>>>(solv_Whh, solu_Whh, xg,
      nullptr, nullptr, L0vh, L0uh, 0, 0);

  // ---- layer 1 (scan writes fp32 Hb/Gb + fp16 Hh/Gh) ----
  xg_mfma<<<dim3(64, 4), 256, 0, stream>>>(L0vh, L0uh, Wihh + (size_t)4 * 640 * 320,
      solv_bih, solv_bhh, solu_bih, solu_bhh, xg, 1);
  lstm_scan<<<4, 512, 0, stream>>>(solv_Whh, solu_Whh, xg,
      Hb, Gb, Hh, Gh, 1, 1);

  // ---- attention: S once (fp16), rowsum, scale, P/Q combined ----
  conv_t<<<5120, 256, 0, stream>>>(Hb, HhT);
  conv_t<<<5120, 256, 0, stream>>>(Gb, GhT);
  s_gemm<<<dim3(64, 4), 256, 0, stream>>>(Hh, Gh, AH);
  rowsum_k<<<4096, 256, 0, stream>>>(AH, il);
  scale_k<<<8192, 256, 0, stream>>>(AH, il);
  pq_mfma<<<128, 256, 0, stream>>>(AH, GhT, HhT, Pb, Qb);

  // ---- tail ----
  zero_f<<<3, 256, 0, stream>>>(inp, 640);
  reduce_uv<<<32, 320, 0, stream>>>(Hb, Pb, inp, 0);
  reduce_uv<<<32, 320, 0, stream>>>(Gb, Qb, inp, 300);
  fc1_k<<<8, 256, 0, stream>>>(fc1_w, fc1_b, inp, xf);
  fc2_k<<<1, 256, 0, stream>>>(xf, fc2_w, fc2_b, outp);
}